// Round 4
// baseline (446.456 us; speedup 1.0000x reference)
//
#include <hip/hip_runtime.h>

#define NN_TOT 208896      // 32*96*68 nodes
#define E_TOT  1671168     // NN_TOT*8 edges
#define B_SZ   32
#define T_SZ   96
#define NPF    68          // nodes per frame
#define HID    128
#define NBINS  204         // 208896 / 1024 nodes per bin

typedef _Float16 f16x8 __attribute__((ext_vector_type(8)));
typedef _Float16 f16x2v __attribute__((ext_vector_type(2)));
typedef float f32x4 __attribute__((ext_vector_type(4)));

// ---------------- bin-level edge histogram (replaces per-node k_deg atomics) ----------------
__global__ __launch_bounds__(256) void k_bincount(const int* __restrict__ dst, int* __restrict__ binCnt) {
    __shared__ int hist[NBINS];
    const int tid = threadIdx.x;
    for (int i = tid; i < NBINS; i += 256) hist[i] = 0;
    __syncthreads();
    const int be = blockIdx.x * 2048 + tid * 8;
    int d[8];
    *(int4*)&d[0] = *(const int4*)&dst[be];
    *(int4*)&d[4] = *(const int4*)&dst[be + 4];
#pragma unroll
    for (int j = 0; j < 8; ++j) atomicAdd(&hist[d[j] >> 10], 1);
    __syncthreads();
    for (int i = tid; i < NBINS; i += 256)
        if (hist[i]) atomicAdd(&binCnt[i], hist[i]);
}

// ---------------- scan 204 bin counts -> binOff + seed gcur ----------------
__global__ __launch_bounds__(256) void k_binscan(const int* __restrict__ binCnt, int* __restrict__ binOff,
                                                 int* __restrict__ gcur) {
    __shared__ int ts[256];
    const int tid = threadIdx.x;
    int v = (tid < NBINS) ? binCnt[tid] : 0;
    ts[tid] = v;
    __syncthreads();
    int inc = v;
    for (int off = 1; off < 256; off <<= 1) {
        int add = (tid >= off) ? ts[tid - off] : 0;
        __syncthreads();
        inc += add;
        ts[tid] = inc;
        __syncthreads();
    }
    int excl = inc - v;
    if (tid < NBINS) {
        binOff[tid] = excl;
        gcur[tid] = excl;
    }
    if (tid == NBINS - 1) binOff[NBINS] = E_TOT;
}

// ---------------- CSR pass B: LDS-binned scatter into per-bin segments (dense bursts) ----------------
__global__ __launch_bounds__(256) void k_binscatter(const int* __restrict__ src, const int* __restrict__ dst,
                                                    int* __restrict__ gcur, int2* __restrict__ er_tmp) {
    __shared__ int hist[NBINS];
    __shared__ int lbase[NBINS];
    const int tid = threadIdx.x;
    for (int i = tid; i < NBINS; i += 256) hist[i] = 0;
    __syncthreads();
    const int be = blockIdx.x * 2048 + tid * 8;
    int s[8], d[8], rk[8];
    *(int4*)&s[0] = *(const int4*)&src[be];
    *(int4*)&s[4] = *(const int4*)&src[be + 4];
    *(int4*)&d[0] = *(const int4*)&dst[be];
    *(int4*)&d[4] = *(const int4*)&dst[be + 4];
#pragma unroll
    for (int j = 0; j < 8; ++j) rk[j] = atomicAdd(&hist[d[j] >> 10], 1);
    __syncthreads();
    for (int i = tid; i < NBINS; i += 256) lbase[i] = atomicAdd(&gcur[i], hist[i]);
    __syncthreads();
#pragma unroll
    for (int j = 0; j < 8; ++j) er_tmp[lbase[d[j] >> 10] + rk[j]] = make_int2(s[j], d[j]);
}

// ---------------- CSR pass C: per-bin degree count (LDS) + local scan -> row_off, xd, sorted er ----
// Also emits xd[i] = (x*is, is): factorized GCN norm (edge_norm = is_src*is_dst).
__global__ __launch_bounds__(256) void k_binsort2(const int2* __restrict__ er_tmp, const int* __restrict__ binOff,
                                                  const float* __restrict__ x, int* __restrict__ er,
                                                  int* __restrict__ row_off, float4* __restrict__ xd) {
    __shared__ int lcnt[1024];
    __shared__ int lofs[1024];
    __shared__ int ts[256];
    const int tid = threadIdx.x;
    const int nb = blockIdx.x << 10;
    for (int i = tid; i < 1024; i += 256) lcnt[i] = 0;
    __syncthreads();
    const int beg = binOff[blockIdx.x], end = binOff[blockIdx.x + 1];
    for (int e = beg + tid; e < end; e += 256) {
        int2 ed = er_tmp[e];
        atomicAdd(&lcnt[ed.y - nb], 1);
    }
    __syncthreads();
    const int base = tid * 4;
    const int c0 = lcnt[base], c1 = lcnt[base + 1], c2 = lcnt[base + 2], c3 = lcnt[base + 3];
    int ssum = c0 + c1 + c2 + c3;
    ts[tid] = ssum;
    __syncthreads();
    int inc = ssum;
    for (int off = 1; off < 256; off <<= 1) {
        int add = (tid >= off) ? ts[tid - off] : 0;
        __syncthreads();
        inc += add;
        ts[tid] = inc;
        __syncthreads();
    }
    const int b0 = beg + (inc - ssum);  // absolute exclusive offset of node base
    lofs[base] = b0;
    lofs[base + 1] = b0 + c0;
    lofs[base + 2] = b0 + c0 + c1;
    lofs[base + 3] = b0 + c0 + c1 + c2;
    row_off[nb + base] = b0;
    row_off[nb + base + 1] = b0 + c0;
    row_off[nb + base + 2] = b0 + c0 + c1;
    row_off[nb + base + 3] = b0 + c0 + c1 + c2;
    if (blockIdx.x == NBINS - 1 && tid == 0) row_off[NN_TOT] = E_TOT;
    // xd pack: 12 contiguous floats = 3 float4 per thread (48B aligned)
    {
        const float4* xv = (const float4*)(x + 3 * (size_t)(nb + base));
        float4 a = xv[0], b = xv[1], c = xv[2];
        float i0 = 1.0f / sqrtf(1.f + (float)c0);
        float i1 = 1.0f / sqrtf(1.f + (float)c1);
        float i2 = 1.0f / sqrtf(1.f + (float)c2);
        float i3 = 1.0f / sqrtf(1.f + (float)c3);
        xd[nb + base + 0] = make_float4(a.x * i0, a.y * i0, a.z * i0, i0);
        xd[nb + base + 1] = make_float4(a.w * i1, b.x * i1, b.y * i1, i1);
        xd[nb + base + 2] = make_float4(b.z * i2, b.w * i2, c.x * i2, i2);
        xd[nb + base + 3] = make_float4(c.y * i3, c.z * i3, c.w * i3, i3);
    }
    __syncthreads();
    for (int e = beg + tid; e < end; e += 256) {
        int2 ed = er_tmp[e];
        int p = atomicAdd(&lofs[ed.y - nb], 1);
        er[p] = ed.x;  // src only: norm comes factorized via xd/z0.w
    }
}

// ---------------- z0: 3-dim GCN0 aggregate, factorized norm -> float4 (z0, is) ----------------
// z0_i = is_i * (sum_src xd[src].xyz + xd[i].xyz);  z0.w = is_i
__global__ __launch_bounds__(256) void k_z0(const float4* __restrict__ xd, const int* __restrict__ row_off,
                                            const int* __restrict__ er, float4* __restrict__ z0out) {
    const int tid = threadIdx.x;
    const int blk = blockIdx.x;
    const int li = tid >> 2;         // local node 0..63
    const int slot = tid & 3;        // edge slot
    const int n = blk * 64 + li;
    const int beg = row_off[n], end = row_off[n + 1];
    float p0 = 0.f, p1 = 0.f, p2 = 0.f;
    for (int ei = beg + slot; ei < end; ei += 4) {
        float4 f = xd[er[ei]];
        p0 += f.x;
        p1 += f.y;
        p2 += f.z;
    }
    p0 += __shfl_xor(p0, 1); p1 += __shfl_xor(p1, 1); p2 += __shfl_xor(p2, 1);
    p0 += __shfl_xor(p0, 2); p1 += __shfl_xor(p1, 2); p2 += __shfl_xor(p2, 2);
    if (slot == 0) {
        const float4 own = xd[n];
        const float w = own.w;
        float4 z;
        z.x = w * (p0 + own.x);
        z.y = w * (p1 + own.y);
        z.z = w * (p2 + own.z);
        z.w = w;
        z0out[n] = z;
    }
}

// ---------------- fused: aggregation w/ packed-f16 h0 recompute + GEMM1 MFMA -> h1 ----------------
// agg_i = is_i * ( sum_src relu(W0 z0_src + b0) * is_src + relu(W0 z0_i + b0) * is_i )
__global__ __launch_bounds__(256, 4) void k_agg_mm(const float4* __restrict__ z0, const int* __restrict__ row_off,
                                                   const int* __restrict__ er, const _Float16* __restrict__ W0h,
                                                   const _Float16* __restrict__ b0h, const _Float16* __restrict__ W1p,
                                                   const float* __restrict__ b1, _Float16* __restrict__ h1) {
    __shared__ __align__(16) _Float16 As[64 * 136];  // rows padded to 136 f16 (272 B)
    const int tid = threadIdx.x;
    const int w = tid >> 6, lane = tid & 63;
    const int blk = blockIdx.x;

    // phase 1: per-lane edge loop, packed f16, all 32 cols in one pass
    {
        const int node = blk * 64 + lane;
        const int beg = row_off[node], end = row_off[node + 1];
        const f16x2v* __restrict__ W0p = (const f16x2v*)W0h;  // [3*64] pairs
        const f16x2v* __restrict__ b0p = (const f16x2v*)b0h;  // [64] pairs
        const int pb = w * 16;
        const f16x2v zero2 = {(_Float16)0.f, (_Float16)0.f};
        f16x2v w0p[16], w1p[16], w2p[16], bbp[16];
#pragma unroll
        for (int j = 0; j < 16; ++j) {
            w0p[j] = W0p[pb + j];
            w1p[j] = W0p[64 + pb + j];
            w2p[j] = W0p[128 + pb + j];
            bbp[j] = b0p[pb + j];
        }
        const float4 zs = z0[node];
        const _Float16 isd = (_Float16)zs.w;
        const f16x2v dnn = {isd, isd};
        f16x2v accp[16];
        {  // self term: factor inside bracket is is_i
            _Float16 sx = (_Float16)zs.x, sy = (_Float16)zs.y, sz = (_Float16)zs.z;
            f16x2v zxx = {sx, sx}, zyy = {sy, sy}, zzz = {sz, sz};
#pragma unroll
            for (int j = 0; j < 16; ++j) {
                f16x2v t = zxx * w0p[j] + (zyy * w1p[j] + (zzz * w2p[j] + bbp[j]));
                t = __builtin_elementwise_max(t, zero2);
                accp[j] = t * dnn;
            }
        }
        int ei = beg;
        for (; ei + 2 <= end; ei += 2) {
            int sa = er[ei], sb = er[ei + 1];
            float4 za = z0[sa];
            float4 zb = z0[sb];
            _Float16 ax = (_Float16)za.x, ay = (_Float16)za.y, az = (_Float16)za.z;
            _Float16 aen = (_Float16)za.w;
            _Float16 bx = (_Float16)zb.x, by = (_Float16)zb.y, bz = (_Float16)zb.z;
            _Float16 ben = (_Float16)zb.w;
            f16x2v axx = {ax, ax}, ayy = {ay, ay}, azz = {az, az}, aee = {aen, aen};
            f16x2v bxx = {bx, bx}, byy = {by, by}, bzz = {bz, bz}, bee = {ben, ben};
#pragma unroll
            for (int j = 0; j < 16; ++j) {
                f16x2v t = axx * w0p[j] + (ayy * w1p[j] + (azz * w2p[j] + bbp[j]));
                t = __builtin_elementwise_max(t, zero2);
                accp[j] = t * aee + accp[j];
            }
#pragma unroll
            for (int j = 0; j < 16; ++j) {
                f16x2v t = bxx * w0p[j] + (byy * w1p[j] + (bzz * w2p[j] + bbp[j]));
                t = __builtin_elementwise_max(t, zero2);
                accp[j] = t * bee + accp[j];
            }
        }
        if (ei < end) {
            float4 za = z0[er[ei]];
            _Float16 ax = (_Float16)za.x, ay = (_Float16)za.y, az = (_Float16)za.z;
            _Float16 aen = (_Float16)za.w;
            f16x2v axx = {ax, ax}, ayy = {ay, ay}, azz = {az, az}, aee = {aen, aen};
#pragma unroll
            for (int j = 0; j < 16; ++j) {
                f16x2v t = axx * w0p[j] + (ayy * w1p[j] + (azz * w2p[j] + bbp[j]));
                t = __builtin_elementwise_max(t, zero2);
                accp[j] = t * aee + accp[j];
            }
        }
        _Float16* dst = &As[lane * 136 + w * 32];
#pragma unroll
        for (int j = 0; j < 16; ++j) *(f16x2v*)(dst + 2 * j) = accp[j] * dnn;  // final * is_i
    }
    __syncthreads();

    // phase 2: MFMA 16x128x128; wave w owns m-tile rows w*16..w*16+15
    const int q = lane >> 4, c = lane & 15;
    f16x8 afr[4];
#pragma unroll
    for (int kk = 0; kk < 4; ++kk) afr[kk] = *(const f16x8*)(&As[(w * 16 + c) * 136 + kk * 32 + q * 8]);
    const f16x8* __restrict__ Bv = (const f16x8*)W1p;
    _Float16* Cst = &As[w * 2176];
#pragma unroll
    for (int j = 0; j < 8; ++j) {
        f32x4 cc = {0.f, 0.f, 0.f, 0.f};
#pragma unroll
        for (int kk = 0; kk < 4; ++kk)
            cc = __builtin_amdgcn_mfma_f32_16x16x32_f16(afr[kk], Bv[(j * 4 + kk) * 64 + lane], cc, 0, 0, 0);
        const float bi = b1[j * 16 + c];
#pragma unroll
        for (int r = 0; r < 4; ++r) Cst[(q * 4 + r) * 128 + j * 16 + c] = (_Float16)fmaxf(cc[r] + bi, 0.f);
    }
#pragma unroll
    for (int it = 0; it < 4; ++it) {
        int idx = it * 64 + lane;
        *(f16x8*)(h1 + (size_t)(blk * 64 + w * 16) * 128 + idx * 8) = *(const f16x8*)(&As[w * 2176 + idx * 8]);
    }
}

// ---------------- weight prep: WihT (f32) + f16 packs: W0h/b0h, W1p/Wmp frags, Whh frags ---------
__global__ __launch_bounds__(256) void k_prep(const float* __restrict__ Wih, const float* __restrict__ Whh,
                                              const float* __restrict__ W1, const float* __restrict__ Wm,
                                              const float* __restrict__ W0, const float* __restrict__ b0,
                                              float* __restrict__ WihT, _Float16* __restrict__ W1p,
                                              _Float16* __restrict__ Wmp, _Float16* __restrict__ Whhp,
                                              _Float16* __restrict__ W0h, _Float16* __restrict__ b0h) {
    int i = blockIdx.x * 256 + threadIdx.x;  // 0..49151
    {
        int o = i >> 7, k = i & 127;
        WihT[k * 384 + o] = Wih[i];
    }
    {
        // Whh frag pack: i = (f*64 + lane)*8 + e, f = (wv*3+g)*4+kk
        int e = i & 7;
        int lane = (i >> 3) & 63;
        int f = i >> 9;  // 0..95
        int kk = f & 3, g = (f >> 2) % 3, wv = f / 12;
        int q = lane >> 4, c = lane & 15;
        Whhp[i] = (_Float16)Whh[(size_t)(g * 128 + 16 * wv + c) * 128 + kk * 32 + q * 8 + e];
    }
    if (i < 16384) {
        int f = i >> 9;          // frag id 0..31
        int j = f >> 2, kk = f & 3;
        int lane = (i >> 3) & 63;
        int e = i & 7;
        int q = lane >> 4, p = lane & 15;
        int k = kk * 32 + q * 8 + e, n = j * 16 + p;
        W1p[i] = (_Float16)W1[k * 128 + n];
        Wmp[i] = (_Float16)Wm[k * 128 + n];
    }
    if (i < 384) W0h[i] = (_Float16)W0[i];
    if (i < 128) b0h[i] = (_Float16)b0[i];
}

// ---------------- fused: GEMM2 (f16 MFMA) + relu + frame mean + gi precompute ----
// gi folding: r,z channels store -log2e*(gi + b_ih + b_hh); n channel stores gi + b_ih.
// Output layout GIt3[B/8][t][o:384][b:8] — per-GRU-block-step slices are contiguous 12KB
// (enables coalesced LDS staging + b128 gate reads in k_gru).
__global__ __launch_bounds__(256) void k_mm_pool(const _Float16* __restrict__ h1, const _Float16* __restrict__ Wmp,
                                                 const float* __restrict__ bm, const float* __restrict__ WihT,
                                                 const float* __restrict__ bih, const float* __restrict__ bhh,
                                                 float* __restrict__ GIt) {
    __shared__ __align__(16) _Float16 As[80 * 136];
    __shared__ float colpart[4 * 128];
    __shared__ float fr[128];
    const int tid = threadIdx.x;
    const int w = tid >> 6, lane = tid & 63;
    const int q = lane >> 4, c = lane & 15;
    const int bt = blockIdx.x;
    const int bb = bt / T_SZ, tt = bt % T_SZ;

    const f16x8* __restrict__ srcv = (const f16x8*)(h1 + (size_t)bt * NPF * HID);
    for (int idx = tid; idx < 80 * 17; idx += 256) {
        int row = idx / 17, ch = idx % 17;
        f16x8 v;
        if (row < NPF && ch < 16) {
            v = srcv[row * 16 + ch];
        } else {
#pragma unroll
            for (int k = 0; k < 8; ++k) v[k] = (_Float16)0.f;
        }
        *(f16x8*)(&As[row * 136 + ch * 8]) = v;
    }
    __syncthreads();

    const f16x8* __restrict__ Bv = (const f16x8*)Wmp;
    const int npass = (w == 0) ? 2 : 1;
    for (int pass = 0; pass < npass; ++pass) {
        const int mt = pass ? 4 : w;
        f16x8 afr[4];
#pragma unroll
        for (int kk = 0; kk < 4; ++kk) afr[kk] = *(const f16x8*)(&As[(mt * 16 + c) * 136 + kk * 32 + q * 8]);
#pragma unroll
        for (int j = 0; j < 8; ++j) {
            f32x4 cc = {0.f, 0.f, 0.f, 0.f};
#pragma unroll
            for (int kk = 0; kk < 4; ++kk)
                cc = __builtin_amdgcn_mfma_f32_16x16x32_f16(afr[kk], Bv[(j * 4 + kk) * 64 + lane], cc, 0, 0, 0);
            const float bi = bm[j * 16 + c];
            float s = 0.f;
#pragma unroll
            for (int r = 0; r < 4; ++r) {
                int m = mt * 16 + q * 4 + r;
                float v = fmaxf(cc[r] + bi, 0.f);
                s += (m < NPF) ? v : 0.f;
            }
            s += __shfl_xor(s, 16);
            s += __shfl_xor(s, 32);
            if (lane < 16) {
                float* dst = &colpart[w * 128 + j * 16 + c];
                *dst = (pass == 0) ? s : (*dst + s);
            }
        }
    }
    __syncthreads();
    if (tid < 128)
        fr[tid] = (colpart[tid] + colpart[128 + tid] + colpart[256 + tid] + colpart[384 + tid]) * (1.0f / NPF);
    __syncthreads();
    if (tid < 128) {
        const size_t sl = ((size_t)(bb >> 3) * 98 + tt) * 3072 + (bb & 7);
#pragma unroll
        for (int p = 0; p < 3; ++p) {
            int o = tid + p * 128;
            float a = bih[o] + ((p < 2) ? bhh[o] : 0.f);
#pragma unroll 8
            for (int k = 0; k < 128; ++k) a = fmaf(fr[k], WihT[k * 384 + o], a);
            if (p < 2) a *= -1.44269504f;  // fold sigmoid's -log2e pre-scale
            GIt[sl + (size_t)o * 8] = a;   // [B4][t][o][b]
        }
    }
}

// ---------------- GRU recurrence: 4 blocks x 8 batches, 4 waves, 2 col-tiles/wave ------
// GIt slices are LDS triple-buffered via async reg-staging (T14): body t issues 3
// coalesced dwordx4 loads for slice t+2 and ds-writes the previously staged slice t+1;
// the compiler's inserted wait is vmcnt(3) (counted, never 0) so HBM/L3 latency hides
// under two full bodies. Soft barrier: lgkmcnt(0)+s_barrier (no vmcnt drain).
#define GRU_SYNC()                                              \
    asm volatile("s_waitcnt lgkmcnt(0)" ::: "memory");          \
    __builtin_amdgcn_s_barrier();                               \
    __builtin_amdgcn_sched_barrier(0);

// Wave w owns col-tiles 2w, 2w+1. Gate phase: lane (q,c) handles batch gb+r=(q&1)*4+r
// at col gcol=(2w+(q>>1))*16+c; tile-1 cc reaches lanes q>=2 via __shfl_xor(.,32).
#define GRU_BODY(PAR, SL, WSL, STC, STP)                                                             \
    {                                                                                                \
        _Pragma("unroll") for (int i = 0; i < 3; ++i)                                                \
            STC[i] = *(const float4*)(sp + i * 256 + sidx);  /* slice t+2 -> regs */                 \
        const _Float16* rb = hbuf[PAR];                                                              \
        _Float16* wb = hbuf[PAR ^ 1];                                                                \
        f16x8 afr[4];                                                                                \
        _Pragma("unroll") for (int kk = 0; kk < 4; ++kk)                                             \
            afr[kk] = *(const f16x8*)(&rb[c * 144 + kk * 32 + q * 8]);                               \
        const float4 gu0 = *(const float4*)(&gbuf[SL][go0]);                                         \
        const float4 gu1 = *(const float4*)(&gbuf[SL][go0 + 1024]);                                  \
        const float4 gu2 = *(const float4*)(&gbuf[SL][go0 + 2048]);                                  \
        f32x4 cc0[3], cc1[3];                                                                        \
        _Pragma("unroll") for (int g = 0; g < 3; ++g) {                                              \
            f32x4 a = {0.f, 0.f, 0.f, 0.f};                                                          \
            _Pragma("unroll") for (int kk = 0; kk < 4; ++kk)                                         \
                a = __builtin_amdgcn_mfma_f32_16x16x32_f16(afr[kk], bfr[0][g][kk], a, 0, 0, 0);      \
            cc0[g] = a;                                                                              \
            f32x4 b = {0.f, 0.f, 0.f, 0.f};                                                          \
            _Pragma("unroll") for (int kk = 0; kk < 4; ++kk)                                         \
                b = __builtin_amdgcn_mfma_f32_16x16x32_f16(afr[kk], bfr[1][g][kk], b, 0, 0, 0);      \
            cc1[g] = b;                                                                              \
        }                                                                                            \
        _Pragma("unroll") for (int r = 0; r < 4; ++r) {                                              \
            float x0 = __shfl_xor(cc1[0][r], 32);                                                    \
            float x1 = __shfl_xor(cc1[1][r], 32);                                                    \
            float x2 = __shfl_xor(cc1[2][r], 32);                                                    \
            float s0 = lowq ? cc0[0][r] : x0;                                                        \
            float s1 = lowq ? cc0[1][r] : x1;                                                        \
            float s2 = lowq ? cc0[2][r] : x2;                                                        \
            float hn = s2 + bh2;                                                                     \
            float rg = __builtin_amdgcn_rcpf(1.f + exp2f(fmaf(mL2E, s0, gu0[r])));                   \
            float zg = __builtin_amdgcn_rcpf(1.f + exp2f(fmaf(mL2E, s1, gu1[r])));                   \
            float arg = fmaf(rg, hn, gu2[r]);                                                        \
            float u = __builtin_amdgcn_rcpf(exp2f(2.f * L2E * arg) + 1.f);                           \
            float nn = fmaf(-2.f, u, 1.f);                                                           \
            h[r] = fmaf(zg, h[r] - nn, nn);                                                          \
            wb[(gb + r) * 144 + gcol] = (_Float16)h[r];                                              \
        }                                                                                            \
        _Pragma("unroll") for (int i = 0; i < 3; ++i)  /* slice t+1 regs -> LDS (vmcnt(3)) */        \
            *(float4*)(&gbuf[WSL][w * 768 + i * 256 + (lane << 2)]) = STP[i];                        \
        sp += 3072;                                                                                  \
        GRU_SYNC()                                                                                   \
    }

__global__ __launch_bounds__(256) __attribute__((amdgpu_waves_per_eu(1, 1)))
void k_gru(const float* __restrict__ GIt, const _Float16* __restrict__ Whhp,
           const float* __restrict__ bhh, float* __restrict__ hT) {
    __shared__ __align__(16) _Float16 hbuf[2][16 * 144];
    __shared__ __align__(16) float gbuf[3][3072];  // triple-buffered GIt slices [o:384][b:8]
    const int tid = threadIdx.x;
    const int w = tid >> 6, lane = tid & 63;
    const int q = lane >> 4, c = lane & 15;
    const bool lowq = (q < 2);
    const int B = blockIdx.x;  // batches 8B..8B+7
    const float L2E = 1.44269504f;
    const float mL2E = -1.44269504f;

    // B-frags for the wave's two col-tiles x 3 gates x 4 k-frags (96 VGPR)
    f16x8 bfr[2][3][4];
#pragma unroll
    for (int t = 0; t < 2; ++t)
#pragma unroll
        for (int g = 0; g < 3; ++g)
#pragma unroll
            for (int kk = 0; kk < 4; ++kk)
                bfr[t][g][kk] =
                    *(const f16x8*)(Whhp + (size_t)((((2 * w + t) * 3 + g) * 4 + kk) * 64 + lane) * 8);
    const int gb = (q & 1) * 4;                      // gate-phase batch base
    const int gcol = (2 * w + (q >> 1)) * 16 + c;    // gate-phase column
    const int go0 = gcol * 8 + gb;                   // gbuf float offset for g=0
    const float bh2 = bhh[256 + gcol];               // n-gate hh-bias
    const int sidx = w * 768 + (lane << 2);          // staging float offset within slice
    for (int i = tid; i < 2 * 16 * 144 / 2; i += 256) ((unsigned int*)hbuf)[i] = 0u;  // BOTH buffers
    float h[4] = {0.f, 0.f, 0.f, 0.f};

    const float* sp = GIt + (size_t)B * 98 * 3072;  // slice 0 of this block
    float4 sta[3], stb[3];
    // prologue: stage slice 0 -> STA -> gbuf[0]; slice 1 -> STB (kept in regs)
#pragma unroll
    for (int i = 0; i < 3; ++i) sta[i] = *(const float4*)(sp + i * 256 + sidx);
#pragma unroll
    for (int i = 0; i < 3; ++i) stb[i] = *(const float4*)(sp + 3072 + i * 256 + sidx);
#pragma unroll
    for (int i = 0; i < 3; ++i) *(float4*)(&gbuf[0][w * 768 + i * 256 + (lane << 2)]) = sta[i];
    sp += 2 * 3072;  // bodies load slice t+2
    GRU_SYNC()

    for (int it = 0; it < T_SZ / 6; ++it) {
        GRU_BODY(0, 0, 1, sta, stb)
        GRU_BODY(1, 1, 2, stb, sta)
        GRU_BODY(0, 2, 0, sta, stb)
        GRU_BODY(1, 0, 1, stb, sta)
        GRU_BODY(0, 1, 2, sta, stb)
        GRU_BODY(1, 2, 0, stb, sta)
    }
#pragma unroll
    for (int r = 0; r < 4; ++r) hT[(size_t)(B * 8 + gb + r) * 128 + gcol] = h[r];
}

// ---------------- classifier head (384 threads: phase 2 needs 320) ----------------
__global__ __launch_bounds__(384) void k_cls(const float* __restrict__ hT, const float* __restrict__ Wc1,
                                             const float* __restrict__ bc1, const float* __restrict__ Wc2,
                                             const float* __restrict__ bc2, float* __restrict__ out) {
    __shared__ float hid[32 * 64];
    int tid = threadIdx.x;
    for (int idx = tid; idx < 2048; idx += 384) {
        int b = idx >> 6, j = idx & 63;
        float a = bc1[j];
#pragma unroll 8
        for (int k = 0; k < 128; ++k) a = fmaf(hT[b * 128 + k], Wc1[k * 64 + j], a);
        hid[idx] = fmaxf(a, 0.f);
    }
    __syncthreads();
    if (tid < 320) {
        int b = tid / 10, c = tid % 10;
        float a = bc2[c];
#pragma unroll 8
        for (int k = 0; k < 64; ++k) a = fmaf(hid[b * 64 + k], Wc2[k * 10 + c], a);
        out[tid] = a;
    }
}

extern "C" void kernel_launch(void* const* d_in, const int* in_sizes, int n_in, void* d_out, int out_size, void* d_ws,
                              size_t ws_size, hipStream_t stream) {
    const float* x = (const float*)d_in[0];
    const int* ei = (const int*)d_in[1];
    const int* e_src = ei;
    const int* e_dst = ei + E_TOT;
    const float* W0 = (const float*)d_in[2];
    const float* b0 = (const float*)d_in[3];
    const float* W1 = (const float*)d_in[4];
    const float* b1 = (const float*)d_in[5];
    const float* Wm = (const float*)d_in[6];
    const float* bm = (const float*)d_in[7];
    const float* Wih = (const float*)d_in[8];
    const float* Whh = (const float*)d_in[9];
    const float* bih = (const float*)d_in[10];
    const float* bhh = (const float*)d_in[11];
    const float* Wc1 = (const float*)d_in[12];
    const float* bc1 = (const float*)d_in[13];
    const float* Wc2 = (const float*)d_in[14];
    const float* bc2 = (const float*)d_in[15];
    float* out = (float*)d_out;

    char* base = (char*)d_ws;
    size_t off = 0;
    auto alloc = [&](size_t bytes) {
        size_t o = off;
        off = (off + bytes + 255) & ~(size_t)255;
        return o;
    };
    size_t o_bincnt = alloc(256 * 4);
    size_t o_binoff = alloc(256 * 4);
    size_t o_gcur = alloc(256 * 4);
    size_t o_rowoff = alloc((size_t)(NN_TOT + 1) * 4);
    size_t o_er = alloc((size_t)E_TOT * 4);       // src-only edge records (4B)
    size_t o_ertmp = alloc((size_t)E_TOT * 8);
    size_t o_xd = alloc((size_t)NN_TOT * 16);     // (x*is, is)
    size_t o_gi = alloc((size_t)4 * 98 * 3072 * 4);  // GIt3 [B/8][98][384][8] (+2 slice pad)
    size_t o_wiht = alloc((size_t)128 * 384 * 4);
    size_t o_w1p = alloc((size_t)128 * 128 * 2);
    size_t o_wmp = alloc((size_t)128 * 128 * 2);
    size_t o_whhp = alloc((size_t)128 * 384 * 2);
    size_t o_w0h = alloc((size_t)384 * 2);
    size_t o_b0h = alloc((size_t)128 * 2);
    size_t o_ht = alloc((size_t)B_SZ * 128 * 4);
    size_t o_z0 = alloc((size_t)NN_TOT * 16);
    size_t o_h1 = alloc((size_t)NN_TOT * HID * 2);
    if (off > ws_size) return;  // workspace too small -> visible validation failure

    int* binCnt = (int*)(base + o_bincnt);
    int* binOff = (int*)(base + o_binoff);
    int* gcur = (int*)(base + o_gcur);
    int* row_off = (int*)(base + o_rowoff);
    int* er = (int*)(base + o_er);
    int2* er_tmp = (int2*)(base + o_ertmp);
    float4* xd = (float4*)(base + o_xd);
    float* GIt = (float*)(base + o_gi);
    float* WihT = (float*)(base + o_wiht);
    _Float16* W1p = (_Float16*)(base + o_w1p);
    _Float16* Wmp = (_Float16*)(base + o_wmp);
    _Float16* Whhp = (_Float16*)(base + o_whhp);
    _Float16* W0h = (_Float16*)(base + o_w0h);
    _Float16* b0h = (_Float16*)(base + o_b0h);
    float* hT = (float*)(base + o_ht);
    float4* z0 = (float4*)(base + o_z0);
    _Float16* h1 = (_Float16*)(base + o_h1);

    hipMemsetAsync(base + o_bincnt, 0, 256 * 4, stream);  // bin counters only

    k_bincount<<<E_TOT / 2048, 256, 0, stream>>>(e_dst, binCnt);
    k_binscan<<<1, 256, 0, stream>>>(binCnt, binOff, gcur);
    k_binscatter<<<E_TOT / 2048, 256, 0, stream>>>(e_src, e_dst, gcur, er_tmp);
    k_binsort2<<<NBINS, 256, 0, stream>>>(er_tmp, binOff, x, er, row_off, xd);
    k_prep<<<(384 * 128) / 256, 256, 0, stream>>>(Wih, Whh, W1, Wm, W0, b0, WihT, W1p, Wmp, Whhp, W0h, b0h);
    k_z0<<<NN_TOT / 64, 256, 0, stream>>>(xd, row_off, er, z0);
    k_agg_mm<<<NN_TOT / 64, 256, 0, stream>>>(z0, row_off, er, W0h, b0h, W1p, b1, h1);
    k_mm_pool<<<B_SZ * T_SZ, 256, 0, stream>>>(h1, Wmp, bm, WihT, bih, bhh, GIt);
    k_gru<<<4, 256, 0, stream>>>(GIt, Whhp, bhh, hT);
    k_cls<<<1, 384, 0, stream>>>(hT, Wc1, bc1, Wc2, bc2, out);
}

// Round 5
// 405.849 us; speedup vs baseline: 1.1001x; 1.1001x over previous
//
#include <hip/hip_runtime.h>

#define NN_TOT 208896      // 32*96*68 nodes
#define E_TOT  1671168     // NN_TOT*8 edges
#define B_SZ   32
#define T_SZ   96
#define NPF    68          // nodes per frame
#define HID    128
#define NBINS  204         // 208896 / 1024 nodes per bin

typedef _Float16 f16x8 __attribute__((ext_vector_type(8)));
typedef _Float16 f16x2v __attribute__((ext_vector_type(2)));
typedef float f32x4 __attribute__((ext_vector_type(4)));

// ---------------- bin-level edge histogram ----------------
__global__ __launch_bounds__(256) void k_bincount(const int* __restrict__ dst, int* __restrict__ binCnt) {
    __shared__ int hist[NBINS];
    const int tid = threadIdx.x;
    for (int i = tid; i < NBINS; i += 256) hist[i] = 0;
    __syncthreads();
    const int be = blockIdx.x * 2048 + tid * 8;
    int d[8];
    *(int4*)&d[0] = *(const int4*)&dst[be];
    *(int4*)&d[4] = *(const int4*)&dst[be + 4];
#pragma unroll
    for (int j = 0; j < 8; ++j) atomicAdd(&hist[d[j] >> 10], 1);
    __syncthreads();
    for (int i = tid; i < NBINS; i += 256)
        if (hist[i]) atomicAdd(&binCnt[i], hist[i]);
}

// ---------------- scan 204 bin counts -> binOff + seed gcur ----------------
__global__ __launch_bounds__(256) void k_binscan(const int* __restrict__ binCnt, int* __restrict__ binOff,
                                                 int* __restrict__ gcur) {
    __shared__ int ts[256];
    const int tid = threadIdx.x;
    int v = (tid < NBINS) ? binCnt[tid] : 0;
    ts[tid] = v;
    __syncthreads();
    int inc = v;
    for (int off = 1; off < 256; off <<= 1) {
        int add = (tid >= off) ? ts[tid - off] : 0;
        __syncthreads();
        inc += add;
        ts[tid] = inc;
        __syncthreads();
    }
    int excl = inc - v;
    if (tid < NBINS) {
        binOff[tid] = excl;
        gcur[tid] = excl;
    }
    if (tid == NBINS - 1) binOff[NBINS] = E_TOT;
}

// ---------------- CSR pass B: LDS-binned scatter into per-bin segments ----------------
__global__ __launch_bounds__(256) void k_binscatter(const int* __restrict__ src, const int* __restrict__ dst,
                                                    int* __restrict__ gcur, int2* __restrict__ er_tmp) {
    __shared__ int hist[NBINS];
    __shared__ int lbase[NBINS];
    const int tid = threadIdx.x;
    for (int i = tid; i < NBINS; i += 256) hist[i] = 0;
    __syncthreads();
    const int be = blockIdx.x * 2048 + tid * 8;
    int s[8], d[8], rk[8];
    *(int4*)&s[0] = *(const int4*)&src[be];
    *(int4*)&s[4] = *(const int4*)&src[be + 4];
    *(int4*)&d[0] = *(const int4*)&dst[be];
    *(int4*)&d[4] = *(const int4*)&dst[be + 4];
#pragma unroll
    for (int j = 0; j < 8; ++j) rk[j] = atomicAdd(&hist[d[j] >> 10], 1);
    __syncthreads();
    for (int i = tid; i < NBINS; i += 256) lbase[i] = atomicAdd(&gcur[i], hist[i]);
    __syncthreads();
#pragma unroll
    for (int j = 0; j < 8; ++j) er_tmp[lbase[d[j] >> 10] + rk[j]] = make_int2(s[j], d[j]);
}

// ---------------- CSR pass C: per-bin degree count + local scan -> row_off, xd, sorted er ----
__global__ __launch_bounds__(256) void k_binsort2(const int2* __restrict__ er_tmp, const int* __restrict__ binOff,
                                                  const float* __restrict__ x, int* __restrict__ er,
                                                  int* __restrict__ row_off, float4* __restrict__ xd) {
    __shared__ int lcnt[1024];
    __shared__ int lofs[1024];
    __shared__ int ts[256];
    const int tid = threadIdx.x;
    const int nb = blockIdx.x << 10;
    for (int i = tid; i < 1024; i += 256) lcnt[i] = 0;
    __syncthreads();
    const int beg = binOff[blockIdx.x], end = binOff[blockIdx.x + 1];
    for (int e = beg + tid; e < end; e += 256) {
        int2 ed = er_tmp[e];
        atomicAdd(&lcnt[ed.y - nb], 1);
    }
    __syncthreads();
    const int base = tid * 4;
    const int c0 = lcnt[base], c1 = lcnt[base + 1], c2 = lcnt[base + 2], c3 = lcnt[base + 3];
    int ssum = c0 + c1 + c2 + c3;
    ts[tid] = ssum;
    __syncthreads();
    int inc = ssum;
    for (int off = 1; off < 256; off <<= 1) {
        int add = (tid >= off) ? ts[tid - off] : 0;
        __syncthreads();
        inc += add;
        ts[tid] = inc;
        __syncthreads();
    }
    const int b0 = beg + (inc - ssum);
    lofs[base] = b0;
    lofs[base + 1] = b0 + c0;
    lofs[base + 2] = b0 + c0 + c1;
    lofs[base + 3] = b0 + c0 + c1 + c2;
    row_off[nb + base] = b0;
    row_off[nb + base + 1] = b0 + c0;
    row_off[nb + base + 2] = b0 + c0 + c1;
    row_off[nb + base + 3] = b0 + c0 + c1 + c2;
    if (blockIdx.x == NBINS - 1 && tid == 0) row_off[NN_TOT] = E_TOT;
    {
        const float4* xv = (const float4*)(x + 3 * (size_t)(nb + base));
        float4 a = xv[0], b = xv[1], c = xv[2];
        float i0 = 1.0f / sqrtf(1.f + (float)c0);
        float i1 = 1.0f / sqrtf(1.f + (float)c1);
        float i2 = 1.0f / sqrtf(1.f + (float)c2);
        float i3 = 1.0f / sqrtf(1.f + (float)c3);
        xd[nb + base + 0] = make_float4(a.x * i0, a.y * i0, a.z * i0, i0);
        xd[nb + base + 1] = make_float4(a.w * i1, b.x * i1, b.y * i1, i1);
        xd[nb + base + 2] = make_float4(b.z * i2, b.w * i2, c.x * i2, i2);
        xd[nb + base + 3] = make_float4(c.y * i3, c.z * i3, c.w * i3, i3);
    }
    __syncthreads();
    for (int e = beg + tid; e < end; e += 256) {
        int2 ed = er_tmp[e];
        int p = atomicAdd(&lofs[ed.y - nb], 1);
        er[p] = ed.x;
    }
}

// ---------------- z0: 3-dim GCN0 aggregate, factorized norm ----------------
__global__ __launch_bounds__(256) void k_z0(const float4* __restrict__ xd, const int* __restrict__ row_off,
                                            const int* __restrict__ er, float4* __restrict__ z0out) {
    const int tid = threadIdx.x;
    const int blk = blockIdx.x;
    const int li = tid >> 2;
    const int slot = tid & 3;
    const int n = blk * 64 + li;
    const int beg = row_off[n], end = row_off[n + 1];
    float p0 = 0.f, p1 = 0.f, p2 = 0.f;
    for (int ei = beg + slot; ei < end; ei += 4) {
        float4 f = xd[er[ei]];
        p0 += f.x;
        p1 += f.y;
        p2 += f.z;
    }
    p0 += __shfl_xor(p0, 1); p1 += __shfl_xor(p1, 1); p2 += __shfl_xor(p2, 1);
    p0 += __shfl_xor(p0, 2); p1 += __shfl_xor(p1, 2); p2 += __shfl_xor(p2, 2);
    if (slot == 0) {
        const float4 own = xd[n];
        const float w = own.w;
        float4 z;
        z.x = w * (p0 + own.x);
        z.y = w * (p1 + own.y);
        z.z = w * (p2 + own.z);
        z.w = w;
        z0out[n] = z;
    }
}

// ---------------- fused: aggregation w/ packed-f16 h0 recompute + GEMM1 MFMA -> h1 ----------------
__global__ __launch_bounds__(256, 4) void k_agg_mm(const float4* __restrict__ z0, const int* __restrict__ row_off,
                                                   const int* __restrict__ er, const _Float16* __restrict__ W0h,
                                                   const _Float16* __restrict__ b0h, const _Float16* __restrict__ W1p,
                                                   const float* __restrict__ b1, _Float16* __restrict__ h1) {
    __shared__ __align__(16) _Float16 As[64 * 136];
    const int tid = threadIdx.x;
    const int w = tid >> 6, lane = tid & 63;
    const int blk = blockIdx.x;

    {
        const int node = blk * 64 + lane;
        const int beg = row_off[node], end = row_off[node + 1];
        const f16x2v* __restrict__ W0p = (const f16x2v*)W0h;
        const f16x2v* __restrict__ b0p = (const f16x2v*)b0h;
        const int pb = w * 16;
        const f16x2v zero2 = {(_Float16)0.f, (_Float16)0.f};
        f16x2v w0p[16], w1p[16], w2p[16], bbp[16];
#pragma unroll
        for (int j = 0; j < 16; ++j) {
            w0p[j] = W0p[pb + j];
            w1p[j] = W0p[64 + pb + j];
            w2p[j] = W0p[128 + pb + j];
            bbp[j] = b0p[pb + j];
        }
        const float4 zs = z0[node];
        const _Float16 isd = (_Float16)zs.w;
        const f16x2v dnn = {isd, isd};
        f16x2v accp[16];
        {
            _Float16 sx = (_Float16)zs.x, sy = (_Float16)zs.y, sz = (_Float16)zs.z;
            f16x2v zxx = {sx, sx}, zyy = {sy, sy}, zzz = {sz, sz};
#pragma unroll
            for (int j = 0; j < 16; ++j) {
                f16x2v t = zxx * w0p[j] + (zyy * w1p[j] + (zzz * w2p[j] + bbp[j]));
                t = __builtin_elementwise_max(t, zero2);
                accp[j] = t * dnn;
            }
        }
        int ei = beg;
        for (; ei + 2 <= end; ei += 2) {
            int sa = er[ei], sb = er[ei + 1];
            float4 za = z0[sa];
            float4 zb = z0[sb];
            _Float16 ax = (_Float16)za.x, ay = (_Float16)za.y, az = (_Float16)za.z;
            _Float16 aen = (_Float16)za.w;
            _Float16 bx = (_Float16)zb.x, by = (_Float16)zb.y, bz = (_Float16)zb.z;
            _Float16 ben = (_Float16)zb.w;
            f16x2v axx = {ax, ax}, ayy = {ay, ay}, azz = {az, az}, aee = {aen, aen};
            f16x2v bxx = {bx, bx}, byy = {by, by}, bzz = {bz, bz}, bee = {ben, ben};
#pragma unroll
            for (int j = 0; j < 16; ++j) {
                f16x2v t = axx * w0p[j] + (ayy * w1p[j] + (azz * w2p[j] + bbp[j]));
                t = __builtin_elementwise_max(t, zero2);
                accp[j] = t * aee + accp[j];
            }
#pragma unroll
            for (int j = 0; j < 16; ++j) {
                f16x2v t = bxx * w0p[j] + (byy * w1p[j] + (bzz * w2p[j] + bbp[j]));
                t = __builtin_elementwise_max(t, zero2);
                accp[j] = t * bee + accp[j];
            }
        }
        if (ei < end) {
            float4 za = z0[er[ei]];
            _Float16 ax = (_Float16)za.x, ay = (_Float16)za.y, az = (_Float16)za.z;
            _Float16 aen = (_Float16)za.w;
            f16x2v axx = {ax, ax}, ayy = {ay, ay}, azz = {az, az}, aee = {aen, aen};
#pragma unroll
            for (int j = 0; j < 16; ++j) {
                f16x2v t = axx * w0p[j] + (ayy * w1p[j] + (azz * w2p[j] + bbp[j]));
                t = __builtin_elementwise_max(t, zero2);
                accp[j] = t * aee + accp[j];
            }
        }
        _Float16* dst = &As[lane * 136 + w * 32];
#pragma unroll
        for (int j = 0; j < 16; ++j) *(f16x2v*)(dst + 2 * j) = accp[j] * dnn;
    }
    __syncthreads();

    const int q = lane >> 4, c = lane & 15;
    f16x8 afr[4];
#pragma unroll
    for (int kk = 0; kk < 4; ++kk) afr[kk] = *(const f16x8*)(&As[(w * 16 + c) * 136 + kk * 32 + q * 8]);
    const f16x8* __restrict__ Bv = (const f16x8*)W1p;
    _Float16* Cst = &As[w * 2176];
#pragma unroll
    for (int j = 0; j < 8; ++j) {
        f32x4 cc = {0.f, 0.f, 0.f, 0.f};
#pragma unroll
        for (int kk = 0; kk < 4; ++kk)
            cc = __builtin_amdgcn_mfma_f32_16x16x32_f16(afr[kk], Bv[(j * 4 + kk) * 64 + lane], cc, 0, 0, 0);
        const float bi = b1[j * 16 + c];
#pragma unroll
        for (int r = 0; r < 4; ++r) Cst[(q * 4 + r) * 128 + j * 16 + c] = (_Float16)fmaxf(cc[r] + bi, 0.f);
    }
#pragma unroll
    for (int it = 0; it < 4; ++it) {
        int idx = it * 64 + lane;
        *(f16x8*)(h1 + (size_t)(blk * 64 + w * 16) * 128 + idx * 8) = *(const f16x8*)(&As[w * 2176 + idx * 8]);
    }
}

// ---------------- weight prep: f16 packs: Wih hi/lo frags, W0h/b0h, W1p/Wmp frags, Whh frags ----
__global__ __launch_bounds__(256) void k_prep(const float* __restrict__ Wih, const float* __restrict__ Whh,
                                              const float* __restrict__ W1, const float* __restrict__ Wm,
                                              const float* __restrict__ W0, const float* __restrict__ b0,
                                              _Float16* __restrict__ Wihh, _Float16* __restrict__ Wihl,
                                              _Float16* __restrict__ W1p, _Float16* __restrict__ Wmp,
                                              _Float16* __restrict__ Whhp, _Float16* __restrict__ W0h,
                                              _Float16* __restrict__ b0h) {
    int i = blockIdx.x * 256 + threadIdx.x;  // 0..49151
    {
        // Wih split-f16 frag pack: B[k][o] = Wih[o][k]; f = j*4+kk, j=0..23 (N=384)
        int e = i & 7;
        int lane = (i >> 3) & 63;
        int f = i >> 9;  // 0..95
        int j = f >> 2, kk = f & 3;
        int q = lane >> 4, p = lane & 15;
        float wv = Wih[(size_t)(j * 16 + p) * 128 + kk * 32 + q * 8 + e];
        _Float16 hi = (_Float16)wv;
        Wihh[i] = hi;
        Wihl[i] = (_Float16)(wv - (float)hi);
    }
    {
        // Whh frag pack: i = (f*64 + lane)*8 + e, f = (wv*3+g)*4+kk
        int e = i & 7;
        int lane = (i >> 3) & 63;
        int f = i >> 9;  // 0..95
        int kk = f & 3, g = (f >> 2) % 3, wv = f / 12;
        int q = lane >> 4, c = lane & 15;
        Whhp[i] = (_Float16)Whh[(size_t)(g * 128 + 16 * wv + c) * 128 + kk * 32 + q * 8 + e];
    }
    if (i < 16384) {
        int f = i >> 9;          // frag id 0..31
        int j = f >> 2, kk = f & 3;
        int lane = (i >> 3) & 63;
        int e = i & 7;
        int q = lane >> 4, p = lane & 15;
        int k = kk * 32 + q * 8 + e, n = j * 16 + p;
        W1p[i] = (_Float16)W1[k * 128 + n];
        Wmp[i] = (_Float16)Wm[k * 128 + n];
    }
    if (i < 384) W0h[i] = (_Float16)W0[i];
    if (i < 128) b0h[i] = (_Float16)b0[i];
}

// ---------------- fused: GEMM2 (f16 MFMA) + relu + frame mean -> FR (split f16) ----
// The old per-block gi tail (384 serial uncoalesced scalar FMAs on 128 threads) is excised;
// gi is now a real MFMA GEMM (k_gi). FR stored as hi+lo f16 so k_gi keeps f32-grade numerics.
__global__ __launch_bounds__(256) void k_mm_pool(const _Float16* __restrict__ h1, const _Float16* __restrict__ Wmp,
                                                 const float* __restrict__ bm, _Float16* __restrict__ FRh,
                                                 _Float16* __restrict__ FRl) {
    __shared__ __align__(16) _Float16 As[80 * 136];
    __shared__ float colpart[4 * 128];
    const int tid = threadIdx.x;
    const int w = tid >> 6, lane = tid & 63;
    const int q = lane >> 4, c = lane & 15;
    const int bt = blockIdx.x;

    const f16x8* __restrict__ srcv = (const f16x8*)(h1 + (size_t)bt * NPF * HID);
    for (int idx = tid; idx < 80 * 17; idx += 256) {
        int row = idx / 17, ch = idx % 17;
        f16x8 v;
        if (row < NPF && ch < 16) {
            v = srcv[row * 16 + ch];
        } else {
#pragma unroll
            for (int k = 0; k < 8; ++k) v[k] = (_Float16)0.f;
        }
        *(f16x8*)(&As[row * 136 + ch * 8]) = v;
    }
    __syncthreads();

    const f16x8* __restrict__ Bv = (const f16x8*)Wmp;
    const int npass = (w == 0) ? 2 : 1;
    for (int pass = 0; pass < npass; ++pass) {
        const int mt = pass ? 4 : w;
        f16x8 afr[4];
#pragma unroll
        for (int kk = 0; kk < 4; ++kk) afr[kk] = *(const f16x8*)(&As[(mt * 16 + c) * 136 + kk * 32 + q * 8]);
#pragma unroll
        for (int j = 0; j < 8; ++j) {
            f32x4 cc = {0.f, 0.f, 0.f, 0.f};
#pragma unroll
            for (int kk = 0; kk < 4; ++kk)
                cc = __builtin_amdgcn_mfma_f32_16x16x32_f16(afr[kk], Bv[(j * 4 + kk) * 64 + lane], cc, 0, 0, 0);
            const float bi = bm[j * 16 + c];
            float s = 0.f;
#pragma unroll
            for (int r = 0; r < 4; ++r) {
                int m = mt * 16 + q * 4 + r;
                float v = fmaxf(cc[r] + bi, 0.f);
                s += (m < NPF) ? v : 0.f;
            }
            s += __shfl_xor(s, 16);
            s += __shfl_xor(s, 32);
            if (lane < 16) {
                float* dst = &colpart[w * 128 + j * 16 + c];
                *dst = (pass == 0) ? s : (*dst + s);
            }
        }
    }
    __syncthreads();
    if (tid < 128) {
        float v = (colpart[tid] + colpart[128 + tid] + colpart[256 + tid] + colpart[384 + tid]) * (1.0f / NPF);
        _Float16 hi = (_Float16)v;
        FRh[(size_t)bt * 128 + tid] = hi;
        FRl[(size_t)bt * 128 + tid] = (_Float16)(v - (float)hi);
    }
}

// ---------------- gi GEMM: FR[3072x128] @ Wih^T -> GIt (time-major, folded) ----
// Split-f16 (hi*hi + hi*lo + lo*hi) keeps ~f32 fidelity. r,z channels: (gi+bih+bhh)*-log2e;
// n channel: gi+bih. Output GIt[(tt*B+bb)*384+o], row m = bb*96+tt.
__global__ __launch_bounds__(256) void k_gi(const _Float16* __restrict__ FRh, const _Float16* __restrict__ FRl,
                                            const _Float16* __restrict__ Wihh, const _Float16* __restrict__ Wihl,
                                            const float* __restrict__ bih, const float* __restrict__ bhh,
                                            float* __restrict__ GIt) {
    __shared__ __align__(16) _Float16 Ah[64 * 136];
    __shared__ __align__(16) _Float16 Al[64 * 136];
    const int tid = threadIdx.x;
    const int w = tid >> 6, lane = tid & 63;
    const int q = lane >> 4, p = lane & 15;
    const int nb = blockIdx.x * 64;

    const f16x8* __restrict__ sh = (const f16x8*)(FRh + (size_t)nb * 128);
    const f16x8* __restrict__ sl = (const f16x8*)(FRl + (size_t)nb * 128);
    for (int idx = tid; idx < 64 * 16; idx += 256) {
        int row = idx >> 4, ch = idx & 15;
        *(f16x8*)(&Ah[row * 136 + ch * 8]) = sh[idx];
        *(f16x8*)(&Al[row * 136 + ch * 8]) = sl[idx];
    }
    __syncthreads();

    f16x8 ah[4], al[4];
#pragma unroll
    for (int kk = 0; kk < 4; ++kk) {
        ah[kk] = *(const f16x8*)(&Ah[(w * 16 + p) * 136 + kk * 32 + q * 8]);
        al[kk] = *(const f16x8*)(&Al[(w * 16 + p) * 136 + kk * 32 + q * 8]);
    }
    const f16x8* __restrict__ Bh = (const f16x8*)Wihh;
    const f16x8* __restrict__ Bl = (const f16x8*)Wihl;
    // destination row offsets for this lane's 4 C rows
    int dr[4];
#pragma unroll
    for (int r = 0; r < 4; ++r) {
        int m = nb + w * 16 + q * 4 + r;
        int bb = m / 96, tt = m - bb * 96;
        dr[r] = (tt * B_SZ + bb) * 384;
    }
#pragma unroll
    for (int j = 0; j < 24; ++j) {
        f32x4 cc = {0.f, 0.f, 0.f, 0.f};
#pragma unroll
        for (int kk = 0; kk < 4; ++kk)
            cc = __builtin_amdgcn_mfma_f32_16x16x32_f16(ah[kk], Bh[(j * 4 + kk) * 64 + lane], cc, 0, 0, 0);
#pragma unroll
        for (int kk = 0; kk < 4; ++kk)
            cc = __builtin_amdgcn_mfma_f32_16x16x32_f16(ah[kk], Bl[(j * 4 + kk) * 64 + lane], cc, 0, 0, 0);
#pragma unroll
        for (int kk = 0; kk < 4; ++kk)
            cc = __builtin_amdgcn_mfma_f32_16x16x32_f16(al[kk], Bh[(j * 4 + kk) * 64 + lane], cc, 0, 0, 0);
        const int o = j * 16 + p;
        const float bias = bih[o] + ((o < 256) ? bhh[o] : 0.f);
        const float scale = (o < 256) ? -1.44269504f : 1.f;
#pragma unroll
        for (int r = 0; r < 4; ++r) GIt[dr[r] + o] = (cc[r] + bias) * scale;
    }
}

// ---------------- GRU recurrence: batch-split 4 blocks x 8 batches (best measured: R2, 78.5us) ---
#define GRU_SYNC()                                              \
    asm volatile("s_waitcnt lgkmcnt(0)" ::: "memory");          \
    __builtin_amdgcn_s_barrier();                               \
    __builtin_amdgcn_sched_barrier(0);

#define GRU_BODY(PAR, GU, GL, JOFF)                                                                  \
    {                                                                                                \
        const _Float16* rb = hbuf[PAR];                                                              \
        _Float16* wb = hbuf[PAR ^ 1];                                                                \
        f16x8 afr[4];                                                                                \
        _Pragma("unroll") for (int kk = 0; kk < 4; ++kk)                                             \
            afr[kk] = *(const f16x8*)(&rb[c * 144 + kk * 32 + q * 8]);                               \
        const float* lp = pb + (size_t)(JOFF + 2) * STRIDE;                                          \
        _Pragma("unroll") for (int r = 0; r < 4; ++r)                                                \
            _Pragma("unroll") for (int g = 0; g < 3; ++g)                                            \
                GL[r * 3 + g] = lp[r * 384 + g * 128];                                               \
        f32x4 cc[3];                                                                                 \
        _Pragma("unroll") for (int g = 0; g < 3; ++g) {                                              \
            f32x4 a = {0.f, 0.f, 0.f, 0.f};                                                          \
            _Pragma("unroll") for (int kk = 0; kk < 4; ++kk)                                         \
                a = __builtin_amdgcn_mfma_f32_16x16x32_f16(afr[kk], bfr[g][kk], a, 0, 0, 0);         \
            cc[g] = a;                                                                               \
        }                                                                                            \
        _Pragma("unroll") for (int r = 0; r < 4; ++r) {                                              \
            float hn = cc[2][r] + bh2;                                                               \
            float rg = __builtin_amdgcn_rcpf(1.f + exp2f(fmaf(mL2E, cc[0][r], GU[r * 3 + 0])));      \
            float zg = __builtin_amdgcn_rcpf(1.f + exp2f(fmaf(mL2E, cc[1][r], GU[r * 3 + 1])));      \
            float arg = fmaf(rg, hn, GU[r * 3 + 2]);                                                 \
            float u = __builtin_amdgcn_rcpf(exp2f(2.f * L2E * arg) + 1.f);                           \
            float nn = fmaf(-2.f, u, 1.f);                                                           \
            h[r] = fmaf(zg, h[r] - nn, nn);                                                          \
            if (q < 2) wb[(q * 4 + r) * 144 + 16 * w + c] = (_Float16)h[r];                          \
        }                                                                                            \
        GRU_SYNC()                                                                                   \
    }

__global__ __launch_bounds__(512) __attribute__((amdgpu_waves_per_eu(1, 2)))
void k_gru(const float* __restrict__ GIt, const _Float16* __restrict__ Whhp,
           const float* __restrict__ bhh, float* __restrict__ hT) {
    __shared__ __align__(16) _Float16 hbuf[2][16 * 144];
    const int tid = threadIdx.x;
    const int w = tid >> 6, lane = tid & 63;
    const int q = lane >> 4, c = lane & 15;
    const int B = blockIdx.x;  // batches 8B..8B+7
    const float L2E = 1.44269504f;
    const float mL2E = -1.44269504f;
    const int STRIDE = B_SZ * 384;

    f16x8 bfr[3][4];
#pragma unroll
    for (int g = 0; g < 3; ++g)
#pragma unroll
        for (int kk = 0; kk < 4; ++kk)
            bfr[g][kk] = *(const f16x8*)(Whhp + (size_t)(((w * 3 + g) * 4 + kk) * 64 + lane) * 8);
    const float bh2 = bhh[256 + 16 * w + c];
    for (int i = tid; i < 2 * 16 * 144 / 2; i += 512) ((unsigned int*)hbuf)[i] = 0u;
    float h[4] = {0.f, 0.f, 0.f, 0.f};

    const int qq = (q < 2) ? q : 1;
    const float* pb = GIt + (size_t)(B * 8 + qq * 4) * 384 + 16 * w + c;
    float g0[12], g1[12], g2[12];
#pragma unroll
    for (int r = 0; r < 4; ++r)
#pragma unroll
        for (int g = 0; g < 3; ++g) {
            g0[r * 3 + g] = pb[r * 384 + g * 128];
            g1[r * 3 + g] = pb[STRIDE + r * 384 + g * 128];
        }
    GRU_SYNC()

    for (int it = 0; it < T_SZ / 6; ++it) {
        GRU_BODY(0, g0, g2, 0)
        GRU_BODY(1, g1, g0, 1)
        GRU_BODY(0, g2, g1, 2)
        GRU_BODY(1, g0, g2, 3)
        GRU_BODY(0, g1, g0, 4)
        GRU_BODY(1, g2, g1, 5)
        pb += 6 * (size_t)STRIDE;
    }
    if (q < 2) {
#pragma unroll
        for (int r = 0; r < 4; ++r) hT[(size_t)(B * 8 + q * 4 + r) * 128 + 16 * w + c] = h[r];
    }
}

// ---------------- classifier head ----------------
__global__ __launch_bounds__(384) void k_cls(const float* __restrict__ hT, const float* __restrict__ Wc1,
                                             const float* __restrict__ bc1, const float* __restrict__ Wc2,
                                             const float* __restrict__ bc2, float* __restrict__ out) {
    __shared__ float hid[32 * 64];
    int tid = threadIdx.x;
    for (int idx = tid; idx < 2048; idx += 384) {
        int b = idx >> 6, j = idx & 63;
        float a = bc1[j];
#pragma unroll 8
        for (int k = 0; k < 128; ++k) a = fmaf(hT[b * 128 + k], Wc1[k * 64 + j], a);
        hid[idx] = fmaxf(a, 0.f);
    }
    __syncthreads();
    if (tid < 320) {
        int b = tid / 10, c = tid % 10;
        float a = bc2[c];
#pragma unroll 8
        for (int k = 0; k < 64; ++k) a = fmaf(hid[b * 64 + k], Wc2[k * 10 + c], a);
        out[tid] = a;
    }
}

extern "C" void kernel_launch(void* const* d_in, const int* in_sizes, int n_in, void* d_out, int out_size, void* d_ws,
                              size_t ws_size, hipStream_t stream) {
    const float* x = (const float*)d_in[0];
    const int* ei = (const int*)d_in[1];
    const int* e_src = ei;
    const int* e_dst = ei + E_TOT;
    const float* W0 = (const float*)d_in[2];
    const float* b0 = (const float*)d_in[3];
    const float* W1 = (const float*)d_in[4];
    const float* b1 = (const float*)d_in[5];
    const float* Wm = (const float*)d_in[6];
    const float* bm = (const float*)d_in[7];
    const float* Wih = (const float*)d_in[8];
    const float* Whh = (const float*)d_in[9];
    const float* bih = (const float*)d_in[10];
    const float* bhh = (const float*)d_in[11];
    const float* Wc1 = (const float*)d_in[12];
    const float* bc1 = (const float*)d_in[13];
    const float* Wc2 = (const float*)d_in[14];
    const float* bc2 = (const float*)d_in[15];
    float* out = (float*)d_out;

    char* base = (char*)d_ws;
    size_t off = 0;
    auto alloc = [&](size_t bytes) {
        size_t o = off;
        off = (off + bytes + 255) & ~(size_t)255;
        return o;
    };
    size_t o_bincnt = alloc(256 * 4);
    size_t o_binoff = alloc(256 * 4);
    size_t o_gcur = alloc(256 * 4);
    size_t o_rowoff = alloc((size_t)(NN_TOT + 1) * 4);
    size_t o_er = alloc((size_t)E_TOT * 4);
    size_t o_ertmp = alloc((size_t)E_TOT * 8);
    size_t o_xd = alloc((size_t)NN_TOT * 16);
    size_t o_gi = alloc((size_t)(T_SZ + 2) * B_SZ * 384 * 4);  // +2 steps: branchless tail prefetch
    size_t o_wihh = alloc((size_t)384 * 128 * 2);
    size_t o_wihl = alloc((size_t)384 * 128 * 2);
    size_t o_frh = alloc((size_t)B_SZ * T_SZ * 128 * 2);
    size_t o_frl = alloc((size_t)B_SZ * T_SZ * 128 * 2);
    size_t o_w1p = alloc((size_t)128 * 128 * 2);
    size_t o_wmp = alloc((size_t)128 * 128 * 2);
    size_t o_whhp = alloc((size_t)128 * 384 * 2);
    size_t o_w0h = alloc((size_t)384 * 2);
    size_t o_b0h = alloc((size_t)128 * 2);
    size_t o_ht = alloc((size_t)B_SZ * 128 * 4);
    size_t o_z0 = alloc((size_t)NN_TOT * 16);
    size_t o_h1 = alloc((size_t)NN_TOT * HID * 2);
    if (off > ws_size) return;

    int* binCnt = (int*)(base + o_bincnt);
    int* binOff = (int*)(base + o_binoff);
    int* gcur = (int*)(base + o_gcur);
    int* row_off = (int*)(base + o_rowoff);
    int* er = (int*)(base + o_er);
    int2* er_tmp = (int2*)(base + o_ertmp);
    float4* xd = (float4*)(base + o_xd);
    float* GIt = (float*)(base + o_gi);
    _Float16* Wihh = (_Float16*)(base + o_wihh);
    _Float16* Wihl = (_Float16*)(base + o_wihl);
    _Float16* FRh = (_Float16*)(base + o_frh);
    _Float16* FRl = (_Float16*)(base + o_frl);
    _Float16* W1p = (_Float16*)(base + o_w1p);
    _Float16* Wmp = (_Float16*)(base + o_wmp);
    _Float16* Whhp = (_Float16*)(base + o_whhp);
    _Float16* W0h = (_Float16*)(base + o_w0h);
    _Float16* b0h = (_Float16*)(base + o_b0h);
    float* hT = (float*)(base + o_ht);
    float4* z0 = (float4*)(base + o_z0);
    _Float16* h1 = (_Float16*)(base + o_h1);

    hipMemsetAsync(base + o_bincnt, 0, 256 * 4, stream);

    k_bincount<<<E_TOT / 2048, 256, 0, stream>>>(e_dst, binCnt);
    k_binscan<<<1, 256, 0, stream>>>(binCnt, binOff, gcur);
    k_binscatter<<<E_TOT / 2048, 256, 0, stream>>>(e_src, e_dst, gcur, er_tmp);
    k_binsort2<<<NBINS, 256, 0, stream>>>(er_tmp, binOff, x, er, row_off, xd);
    k_prep<<<(384 * 128) / 256, 256, 0, stream>>>(Wih, Whh, W1, Wm, W0, b0, Wihh, Wihl, W1p, Wmp, Whhp, W0h, b0h);
    k_z0<<<NN_TOT / 64, 256, 0, stream>>>(xd, row_off, er, z0);
    k_agg_mm<<<NN_TOT / 64, 256, 0, stream>>>(z0, row_off, er, W0h, b0h, W1p, b1, h1);
    k_mm_pool<<<B_SZ * T_SZ, 256, 0, stream>>>(h1, Wmp, bm, FRh, FRl);
    k_gi<<<B_SZ * T_SZ / 64, 256, 0, stream>>>(FRh, FRl, Wihh, Wihl, bih, bhh, GIt);
    k_gru<<<4, 512, 0, stream>>>(GIt, Whhp, bhh, hT);
    k_cls<<<1, 384, 0, stream>>>(hT, Wc1, bc1, Wc2, bc2, out);
}

// Round 6
// 387.639 us; speedup vs baseline: 1.1517x; 1.0470x over previous
//
#include <hip/hip_runtime.h>

#define NN_TOT 208896      // 32*96*68 nodes
#define E_TOT  1671168     // NN_TOT*8 edges
#define B_SZ   32
#define T_SZ   96
#define NPF    68          // nodes per frame
#define HID    128
#define NBINS  204         // 208896 / 1024 nodes per bin
#define CAP    9216        // padded per-bin capacity: mean 8192 + 11 sigma (overflow p ~ 1e-27)
#define NSB    816         // scatter blocks = E_TOT / 2048

typedef _Float16 f16x8 __attribute__((ext_vector_type(8)));
typedef _Float16 f16x2v __attribute__((ext_vector_type(2)));
typedef float f32x4 __attribute__((ext_vector_type(4)));

// ---------------- single-pass scatter into padded bins (+ fused weight prep blocks) ----------------
// Blocks [0,816): LDS-hist scatter of edges into er_tmp[bin*CAP + cursor] (gcur zero-seeded,
// bin-local cursors — no global scan kernel needed). Blocks [816,1008): weight prep.
__global__ __launch_bounds__(256) void k_scatter(const int* __restrict__ src, const int* __restrict__ dst,
                                                 int* __restrict__ gcur, int2* __restrict__ er_tmp,
                                                 const float* __restrict__ Wih, const float* __restrict__ Whh,
                                                 const float* __restrict__ W1, const float* __restrict__ Wm,
                                                 const float* __restrict__ W0, const float* __restrict__ b0,
                                                 _Float16* __restrict__ Wihh, _Float16* __restrict__ Wihl,
                                                 _Float16* __restrict__ W1p, _Float16* __restrict__ Wmp,
                                                 _Float16* __restrict__ Whhp, _Float16* __restrict__ W0h,
                                                 _Float16* __restrict__ b0h) {
    const int bid = blockIdx.x;
    const int tid = threadIdx.x;
    if (bid >= NSB) {
        // ---- weight prep (uniform per-block branch) ----
        int i = (bid - NSB) * 256 + tid;  // 0..49151
        {
            // Wih split-f16 frag pack: B[k][o] = Wih[o][k]; f = j*4+kk, j=0..23 (N=384)
            int e = i & 7;
            int lane = (i >> 3) & 63;
            int f = i >> 9;  // 0..95
            int j = f >> 2, kk = f & 3;
            int q = lane >> 4, p = lane & 15;
            float wv = Wih[(size_t)(j * 16 + p) * 128 + kk * 32 + q * 8 + e];
            _Float16 hi = (_Float16)wv;
            Wihh[i] = hi;
            Wihl[i] = (_Float16)(wv - (float)hi);
        }
        {
            // Whh frag pack: i = (f*64 + lane)*8 + e, f = (wv*3+g)*4+kk
            int e = i & 7;
            int lane = (i >> 3) & 63;
            int f = i >> 9;  // 0..95
            int kk = f & 3, g = (f >> 2) % 3, wv = f / 12;
            int q = lane >> 4, c = lane & 15;
            Whhp[i] = (_Float16)Whh[(size_t)(g * 128 + 16 * wv + c) * 128 + kk * 32 + q * 8 + e];
        }
        if (i < 16384) {
            int f = i >> 9;          // frag id 0..31
            int j = f >> 2, kk = f & 3;
            int lane = (i >> 3) & 63;
            int e = i & 7;
            int q = lane >> 4, p = lane & 15;
            int k = kk * 32 + q * 8 + e, n = j * 16 + p;
            W1p[i] = (_Float16)W1[k * 128 + n];
            Wmp[i] = (_Float16)Wm[k * 128 + n];
        }
        if (i < 384) W0h[i] = (_Float16)W0[i];
        if (i < 128) b0h[i] = (_Float16)b0[i];
        return;
    }
    __shared__ int hist[NBINS];
    __shared__ int lbase[NBINS];
    for (int i = tid; i < NBINS; i += 256) hist[i] = 0;
    __syncthreads();
    const int be = bid * 2048 + tid * 8;
    int s[8], d[8], rk[8];
    *(int4*)&s[0] = *(const int4*)&src[be];
    *(int4*)&s[4] = *(const int4*)&src[be + 4];
    *(int4*)&d[0] = *(const int4*)&dst[be];
    *(int4*)&d[4] = *(const int4*)&dst[be + 4];
#pragma unroll
    for (int j = 0; j < 8; ++j) rk[j] = atomicAdd(&hist[d[j] >> 10], 1);
    __syncthreads();
    for (int i = tid; i < NBINS; i += 256) lbase[i] = atomicAdd(&gcur[i], hist[i]);
    __syncthreads();
#pragma unroll
    for (int j = 0; j < 8; ++j) {
        int b = d[j] >> 10;
        er_tmp[(size_t)b * CAP + lbase[b] + rk[j]] = make_int2(s[j], d[j]);
    }
}

// ---------------- CSR pass C: per-bin degree count + local scan -> row2 (padded coords), xd, er ----
// row2[n] = (beg,end) into the padded er layout; xd[i] = (x*is, is) — factorized GCN norm.
__global__ __launch_bounds__(256) void k_binsort2(const int2* __restrict__ er_tmp, const int* __restrict__ gcur,
                                                  const float* __restrict__ x, int* __restrict__ er,
                                                  int2* __restrict__ row2, float4* __restrict__ xd) {
    __shared__ int lcnt[1024];
    __shared__ int lofs[1024];
    __shared__ int ts[256];
    const int tid = threadIdx.x;
    const int nb = blockIdx.x << 10;
    const int base0 = blockIdx.x * CAP;
    for (int i = tid; i < 1024; i += 256) lcnt[i] = 0;
    __syncthreads();
    const int end = base0 + gcur[blockIdx.x];
    for (int e = base0 + tid; e < end; e += 256) {
        int2 ed = er_tmp[e];
        atomicAdd(&lcnt[ed.y - nb], 1);
    }
    __syncthreads();
    const int base = tid * 4;
    const int c0 = lcnt[base], c1 = lcnt[base + 1], c2 = lcnt[base + 2], c3 = lcnt[base + 3];
    int ssum = c0 + c1 + c2 + c3;
    ts[tid] = ssum;
    __syncthreads();
    int inc = ssum;
    for (int off = 1; off < 256; off <<= 1) {
        int add = (tid >= off) ? ts[tid - off] : 0;
        __syncthreads();
        inc += add;
        ts[tid] = inc;
        __syncthreads();
    }
    const int b0 = base0 + (inc - ssum);  // padded-coord exclusive offset of node base
    lofs[base] = b0;
    lofs[base + 1] = b0 + c0;
    lofs[base + 2] = b0 + c0 + c1;
    lofs[base + 3] = b0 + c0 + c1 + c2;
    row2[nb + base] = make_int2(b0, b0 + c0);
    row2[nb + base + 1] = make_int2(b0 + c0, b0 + c0 + c1);
    row2[nb + base + 2] = make_int2(b0 + c0 + c1, b0 + c0 + c1 + c2);
    row2[nb + base + 3] = make_int2(b0 + c0 + c1 + c2, b0 + ssum);
    // xd pack: 12 contiguous floats = 3 float4 per thread (48B aligned)
    {
        const float4* xv = (const float4*)(x + 3 * (size_t)(nb + base));
        float4 a = xv[0], b = xv[1], c = xv[2];
        float i0 = 1.0f / sqrtf(1.f + (float)c0);
        float i1 = 1.0f / sqrtf(1.f + (float)c1);
        float i2 = 1.0f / sqrtf(1.f + (float)c2);
        float i3 = 1.0f / sqrtf(1.f + (float)c3);
        xd[nb + base + 0] = make_float4(a.x * i0, a.y * i0, a.z * i0, i0);
        xd[nb + base + 1] = make_float4(a.w * i1, b.x * i1, b.y * i1, i1);
        xd[nb + base + 2] = make_float4(b.z * i2, b.w * i2, c.x * i2, i2);
        xd[nb + base + 3] = make_float4(c.y * i3, c.z * i3, c.w * i3, i3);
    }
    __syncthreads();
    for (int e = base0 + tid; e < end; e += 256) {
        int2 ed = er_tmp[e];
        int p = atomicAdd(&lofs[ed.y - nb], 1);
        er[p] = ed.x;  // src only: norm comes factorized via xd/z0.w
    }
}

// ---------------- z0: 3-dim GCN0 aggregate, factorized norm ----------------
__global__ __launch_bounds__(256) void k_z0(const float4* __restrict__ xd, const int2* __restrict__ row2,
                                            const int* __restrict__ er, float4* __restrict__ z0out) {
    const int tid = threadIdx.x;
    const int blk = blockIdx.x;
    const int li = tid >> 2;
    const int slot = tid & 3;
    const int n = blk * 64 + li;
    const int2 be2 = row2[n];
    float p0 = 0.f, p1 = 0.f, p2 = 0.f;
    for (int ei = be2.x + slot; ei < be2.y; ei += 4) {
        float4 f = xd[er[ei]];
        p0 += f.x;
        p1 += f.y;
        p2 += f.z;
    }
    p0 += __shfl_xor(p0, 1); p1 += __shfl_xor(p1, 1); p2 += __shfl_xor(p2, 1);
    p0 += __shfl_xor(p0, 2); p1 += __shfl_xor(p1, 2); p2 += __shfl_xor(p2, 2);
    if (slot == 0) {
        const float4 own = xd[n];
        const float w = own.w;
        float4 z;
        z.x = w * (p0 + own.x);
        z.y = w * (p1 + own.y);
        z.z = w * (p2 + own.z);
        z.w = w;
        z0out[n] = z;
    }
}

// ---------------- fused: aggregation w/ packed-f16 h0 recompute + GEMM1 MFMA -> h1 ----------------
__global__ __launch_bounds__(256, 4) void k_agg_mm(const float4* __restrict__ z0, const int2* __restrict__ row2,
                                                   const int* __restrict__ er, const _Float16* __restrict__ W0h,
                                                   const _Float16* __restrict__ b0h, const _Float16* __restrict__ W1p,
                                                   const float* __restrict__ b1, _Float16* __restrict__ h1) {
    __shared__ __align__(16) _Float16 As[64 * 136];
    const int tid = threadIdx.x;
    const int w = tid >> 6, lane = tid & 63;
    const int blk = blockIdx.x;

    {
        const int node = blk * 64 + lane;
        const int2 be2 = row2[node];
        const int beg = be2.x, end = be2.y;
        const f16x2v* __restrict__ W0p = (const f16x2v*)W0h;
        const f16x2v* __restrict__ b0p = (const f16x2v*)b0h;
        const int pb = w * 16;
        const f16x2v zero2 = {(_Float16)0.f, (_Float16)0.f};
        f16x2v w0p[16], w1p[16], w2p[16], bbp[16];
#pragma unroll
        for (int j = 0; j < 16; ++j) {
            w0p[j] = W0p[pb + j];
            w1p[j] = W0p[64 + pb + j];
            w2p[j] = W0p[128 + pb + j];
            bbp[j] = b0p[pb + j];
        }
        const float4 zs = z0[node];
        const _Float16 isd = (_Float16)zs.w;
        const f16x2v dnn = {isd, isd};
        f16x2v accp[16];
        {
            _Float16 sx = (_Float16)zs.x, sy = (_Float16)zs.y, sz = (_Float16)zs.z;
            f16x2v zxx = {sx, sx}, zyy = {sy, sy}, zzz = {sz, sz};
#pragma unroll
            for (int j = 0; j < 16; ++j) {
                f16x2v t = zxx * w0p[j] + (zyy * w1p[j] + (zzz * w2p[j] + bbp[j]));
                t = __builtin_elementwise_max(t, zero2);
                accp[j] = t * dnn;
            }
        }
        int ei = beg;
        for (; ei + 2 <= end; ei += 2) {
            int sa = er[ei], sb = er[ei + 1];
            float4 za = z0[sa];
            float4 zb = z0[sb];
            _Float16 ax = (_Float16)za.x, ay = (_Float16)za.y, az = (_Float16)za.z;
            _Float16 aen = (_Float16)za.w;
            _Float16 bx = (_Float16)zb.x, by = (_Float16)zb.y, bz = (_Float16)zb.z;
            _Float16 ben = (_Float16)zb.w;
            f16x2v axx = {ax, ax}, ayy = {ay, ay}, azz = {az, az}, aee = {aen, aen};
            f16x2v bxx = {bx, bx}, byy = {by, by}, bzz = {bz, bz}, bee = {ben, ben};
#pragma unroll
            for (int j = 0; j < 16; ++j) {
                f16x2v t = axx * w0p[j] + (ayy * w1p[j] + (azz * w2p[j] + bbp[j]));
                t = __builtin_elementwise_max(t, zero2);
                accp[j] = t * aee + accp[j];
            }
#pragma unroll
            for (int j = 0; j < 16; ++j) {
                f16x2v t = bxx * w0p[j] + (byy * w1p[j] + (bzz * w2p[j] + bbp[j]));
                t = __builtin_elementwise_max(t, zero2);
                accp[j] = t * bee + accp[j];
            }
        }
        if (ei < end) {
            float4 za = z0[er[ei]];
            _Float16 ax = (_Float16)za.x, ay = (_Float16)za.y, az = (_Float16)za.z;
            _Float16 aen = (_Float16)za.w;
            f16x2v axx = {ax, ax}, ayy = {ay, ay}, azz = {az, az}, aee = {aen, aen};
#pragma unroll
            for (int j = 0; j < 16; ++j) {
                f16x2v t = axx * w0p[j] + (ayy * w1p[j] + (azz * w2p[j] + bbp[j]));
                t = __builtin_elementwise_max(t, zero2);
                accp[j] = t * aee + accp[j];
            }
        }
        _Float16* dst = &As[lane * 136 + w * 32];
#pragma unroll
        for (int j = 0; j < 16; ++j) *(f16x2v*)(dst + 2 * j) = accp[j] * dnn;
    }
    __syncthreads();

    const int q = lane >> 4, c = lane & 15;
    f16x8 afr[4];
#pragma unroll
    for (int kk = 0; kk < 4; ++kk) afr[kk] = *(const f16x8*)(&As[(w * 16 + c) * 136 + kk * 32 + q * 8]);
    const f16x8* __restrict__ Bv = (const f16x8*)W1p;
    _Float16* Cst = &As[w * 2176];
#pragma unroll
    for (int j = 0; j < 8; ++j) {
        f32x4 cc = {0.f, 0.f, 0.f, 0.f};
#pragma unroll
        for (int kk = 0; kk < 4; ++kk)
            cc = __builtin_amdgcn_mfma_f32_16x16x32_f16(afr[kk], Bv[(j * 4 + kk) * 64 + lane], cc, 0, 0, 0);
        const float bi = b1[j * 16 + c];
#pragma unroll
        for (int r = 0; r < 4; ++r) Cst[(q * 4 + r) * 128 + j * 16 + c] = (_Float16)fmaxf(cc[r] + bi, 0.f);
    }
#pragma unroll
    for (int it = 0; it < 4; ++it) {
        int idx = it * 64 + lane;
        *(f16x8*)(h1 + (size_t)(blk * 64 + w * 16) * 128 + idx * 8) = *(const f16x8*)(&As[w * 2176 + idx * 8]);
    }
}

// ---------------- fused: GEMM2 (f16 MFMA) + relu + frame mean -> FR (split f16) ----
__global__ __launch_bounds__(256) void k_mm_pool(const _Float16* __restrict__ h1, const _Float16* __restrict__ Wmp,
                                                 const float* __restrict__ bm, _Float16* __restrict__ FRh,
                                                 _Float16* __restrict__ FRl) {
    __shared__ __align__(16) _Float16 As[80 * 136];
    __shared__ float colpart[4 * 128];
    const int tid = threadIdx.x;
    const int w = tid >> 6, lane = tid & 63;
    const int q = lane >> 4, c = lane & 15;
    const int bt = blockIdx.x;

    const f16x8* __restrict__ srcv = (const f16x8*)(h1 + (size_t)bt * NPF * HID);
    for (int idx = tid; idx < 80 * 17; idx += 256) {
        int row = idx / 17, ch = idx % 17;
        f16x8 v;
        if (row < NPF && ch < 16) {
            v = srcv[row * 16 + ch];
        } else {
#pragma unroll
            for (int k = 0; k < 8; ++k) v[k] = (_Float16)0.f;
        }
        *(f16x8*)(&As[row * 136 + ch * 8]) = v;
    }
    __syncthreads();

    const f16x8* __restrict__ Bv = (const f16x8*)Wmp;
    const int npass = (w == 0) ? 2 : 1;
    for (int pass = 0; pass < npass; ++pass) {
        const int mt = pass ? 4 : w;
        f16x8 afr[4];
#pragma unroll
        for (int kk = 0; kk < 4; ++kk) afr[kk] = *(const f16x8*)(&As[(mt * 16 + c) * 136 + kk * 32 + q * 8]);
#pragma unroll
        for (int j = 0; j < 8; ++j) {
            f32x4 cc = {0.f, 0.f, 0.f, 0.f};
#pragma unroll
            for (int kk = 0; kk < 4; ++kk)
                cc = __builtin_amdgcn_mfma_f32_16x16x32_f16(afr[kk], Bv[(j * 4 + kk) * 64 + lane], cc, 0, 0, 0);
            const float bi = bm[j * 16 + c];
            float s = 0.f;
#pragma unroll
            for (int r = 0; r < 4; ++r) {
                int m = mt * 16 + q * 4 + r;
                float v = fmaxf(cc[r] + bi, 0.f);
                s += (m < NPF) ? v : 0.f;
            }
            s += __shfl_xor(s, 16);
            s += __shfl_xor(s, 32);
            if (lane < 16) {
                float* dst = &colpart[w * 128 + j * 16 + c];
                *dst = (pass == 0) ? s : (*dst + s);
            }
        }
    }
    __syncthreads();
    if (tid < 128) {
        float v = (colpart[tid] + colpart[128 + tid] + colpart[256 + tid] + colpart[384 + tid]) * (1.0f / NPF);
        _Float16 hi = (_Float16)v;
        FRh[(size_t)blockIdx.x * 128 + tid] = hi;
        FRl[(size_t)blockIdx.x * 128 + tid] = (_Float16)(v - (float)hi);
    }
}

// ---------------- gi GEMM: FR[3072x128] @ Wih^T -> GIt (time-major, folded) ----
__global__ __launch_bounds__(256) void k_gi(const _Float16* __restrict__ FRh, const _Float16* __restrict__ FRl,
                                            const _Float16* __restrict__ Wihh, const _Float16* __restrict__ Wihl,
                                            const float* __restrict__ bih, const float* __restrict__ bhh,
                                            float* __restrict__ GIt) {
    __shared__ __align__(16) _Float16 Ah[64 * 136];
    __shared__ __align__(16) _Float16 Al[64 * 136];
    const int tid = threadIdx.x;
    const int w = tid >> 6, lane = tid & 63;
    const int q = lane >> 4, p = lane & 15;
    const int nb = blockIdx.x * 64;

    const f16x8* __restrict__ sh = (const f16x8*)(FRh + (size_t)nb * 128);
    const f16x8* __restrict__ sl = (const f16x8*)(FRl + (size_t)nb * 128);
    for (int idx = tid; idx < 64 * 16; idx += 256) {
        int row = idx >> 4, ch = idx & 15;
        *(f16x8*)(&Ah[row * 136 + ch * 8]) = sh[idx];
        *(f16x8*)(&Al[row * 136 + ch * 8]) = sl[idx];
    }
    __syncthreads();

    f16x8 ah[4], al[4];
#pragma unroll
    for (int kk = 0; kk < 4; ++kk) {
        ah[kk] = *(const f16x8*)(&Ah[(w * 16 + p) * 136 + kk * 32 + q * 8]);
        al[kk] = *(const f16x8*)(&Al[(w * 16 + p) * 136 + kk * 32 + q * 8]);
    }
    const f16x8* __restrict__ Bh = (const f16x8*)Wihh;
    const f16x8* __restrict__ Bl = (const f16x8*)Wihl;
    int dr[4];
#pragma unroll
    for (int r = 0; r < 4; ++r) {
        int m = nb + w * 16 + q * 4 + r;
        int bb = m / 96, tt = m - bb * 96;
        dr[r] = (tt * B_SZ + bb) * 384;
    }
#pragma unroll
    for (int j = 0; j < 24; ++j) {
        f32x4 cc = {0.f, 0.f, 0.f, 0.f};
#pragma unroll
        for (int kk = 0; kk < 4; ++kk)
            cc = __builtin_amdgcn_mfma_f32_16x16x32_f16(ah[kk], Bh[(j * 4 + kk) * 64 + lane], cc, 0, 0, 0);
#pragma unroll
        for (int kk = 0; kk < 4; ++kk)
            cc = __builtin_amdgcn_mfma_f32_16x16x32_f16(ah[kk], Bl[(j * 4 + kk) * 64 + lane], cc, 0, 0, 0);
#pragma unroll
        for (int kk = 0; kk < 4; ++kk)
            cc = __builtin_amdgcn_mfma_f32_16x16x32_f16(al[kk], Bh[(j * 4 + kk) * 64 + lane], cc, 0, 0, 0);
        const int o = j * 16 + p;
        const float bias = bih[o] + ((o < 256) ? bhh[o] : 0.f);
        const float scale = (o < 256) ? -1.44269504f : 1.f;
#pragma unroll
        for (int r = 0; r < 4; ++r) GIt[dr[r] + o] = (cc[r] + bias) * scale;
    }
}

// ---------------- GRU recurrence: batch-split 4 blocks x 8 batches (best measured variant) ------
#define GRU_SYNC()                                              \
    asm volatile("s_waitcnt lgkmcnt(0)" ::: "memory");          \
    __builtin_amdgcn_s_barrier();                               \
    __builtin_amdgcn_sched_barrier(0);

#define GRU_BODY(PAR, GU, GL, JOFF)                                                                  \
    {                                                                                                \
        const _Float16* rb = hbuf[PAR];                                                              \
        _Float16* wb = hbuf[PAR ^ 1];                                                                \
        f16x8 afr[4];                                                                                \
        _Pragma("unroll") for (int kk = 0; kk < 4; ++kk)                                             \
            afr[kk] = *(const f16x8*)(&rb[c * 144 + kk * 32 + q * 8]);                               \
        const float* lp = pb + (size_t)(JOFF + 2) * STRIDE;                                          \
        _Pragma("unroll") for (int r = 0; r < 4; ++r)                                                \
            _Pragma("unroll") for (int g = 0; g < 3; ++g)                                            \
                GL[r * 3 + g] = lp[r * 384 + g * 128];                                               \
        f32x4 cc[3];                                                                                 \
        _Pragma("unroll") for (int g = 0; g < 3; ++g) {                                              \
            f32x4 a = {0.f, 0.f, 0.f, 0.f};                                                          \
            _Pragma("unroll") for (int kk = 0; kk < 4; ++kk)                                         \
                a = __builtin_amdgcn_mfma_f32_16x16x32_f16(afr[kk], bfr[g][kk], a, 0, 0, 0);         \
            cc[g] = a;                                                                               \
        }                                                                                            \
        _Pragma("unroll") for (int r = 0; r < 4; ++r) {                                              \
            float hn = cc[2][r] + bh2;                                                               \
            float rg = __builtin_amdgcn_rcpf(1.f + exp2f(fmaf(mL2E, cc[0][r], GU[r * 3 + 0])));      \
            float zg = __builtin_amdgcn_rcpf(1.f + exp2f(fmaf(mL2E, cc[1][r], GU[r * 3 + 1])));      \
            float arg = fmaf(rg, hn, GU[r * 3 + 2]);                                                 \
            float u = __builtin_amdgcn_rcpf(exp2f(2.f * L2E * arg) + 1.f);                           \
            float nn = fmaf(-2.f, u, 1.f);                                                           \
            h[r] = fmaf(zg, h[r] - nn, nn);                                                          \
            if (q < 2) wb[(q * 4 + r) * 144 + 16 * w + c] = (_Float16)h[r];                          \
        }                                                                                            \
        GRU_SYNC()                                                                                   \
    }

__global__ __launch_bounds__(512) __attribute__((amdgpu_waves_per_eu(1, 2)))
void k_gru(const float* __restrict__ GIt, const _Float16* __restrict__ Whhp,
           const float* __restrict__ bhh, float* __restrict__ hT) {
    __shared__ __align__(16) _Float16 hbuf[2][16 * 144];
    const int tid = threadIdx.x;
    const int w = tid >> 6, lane = tid & 63;
    const int q = lane >> 4, c = lane & 15;
    const int B = blockIdx.x;  // batches 8B..8B+7
    const float L2E = 1.44269504f;
    const float mL2E = -1.44269504f;
    const int STRIDE = B_SZ * 384;

    f16x8 bfr[3][4];
#pragma unroll
    for (int g = 0; g < 3; ++g)
#pragma unroll
        for (int kk = 0; kk < 4; ++kk)
            bfr[g][kk] = *(const f16x8*)(Whhp + (size_t)(((w * 3 + g) * 4 + kk) * 64 + lane) * 8);
    const float bh2 = bhh[256 + 16 * w + c];
    for (int i = tid; i < 2 * 16 * 144 / 2; i += 512) ((unsigned int*)hbuf)[i] = 0u;
    float h[4] = {0.f, 0.f, 0.f, 0.f};

    const int qq = (q < 2) ? q : 1;
    const float* pb = GIt + (size_t)(B * 8 + qq * 4) * 384 + 16 * w + c;
    float g0[12], g1[12], g2[12];
#pragma unroll
    for (int r = 0; r < 4; ++r)
#pragma unroll
        for (int g = 0; g < 3; ++g) {
            g0[r * 3 + g] = pb[r * 384 + g * 128];
            g1[r * 3 + g] = pb[STRIDE + r * 384 + g * 128];
        }
    GRU_SYNC()

    for (int it = 0; it < T_SZ / 6; ++it) {
        GRU_BODY(0, g0, g2, 0)
        GRU_BODY(1, g1, g0, 1)
        GRU_BODY(0, g2, g1, 2)
        GRU_BODY(1, g0, g2, 3)
        GRU_BODY(0, g1, g0, 4)
        GRU_BODY(1, g2, g1, 5)
        pb += 6 * (size_t)STRIDE;
    }
    if (q < 2) {
#pragma unroll
        for (int r = 0; r < 4; ++r) hT[(size_t)(B * 8 + q * 4 + r) * 128 + 16 * w + c] = h[r];
    }
}

// ---------------- classifier head ----------------
__global__ __launch_bounds__(384) void k_cls(const float* __restrict__ hT, const float* __restrict__ Wc1,
                                             const float* __restrict__ bc1, const float* __restrict__ Wc2,
                                             const float* __restrict__ bc2, float* __restrict__ out) {
    __shared__ float hid[32 * 64];
    int tid = threadIdx.x;
    for (int idx = tid; idx < 2048; idx += 384) {
        int b = idx >> 6, j = idx & 63;
        float a = bc1[j];
#pragma unroll 8
        for (int k = 0; k < 128; ++k) a = fmaf(hT[b * 128 + k], Wc1[k * 64 + j], a);
        hid[idx] = fmaxf(a, 0.f);
    }
    __syncthreads();
    if (tid < 320) {
        int b = tid / 10, c = tid % 10;
        float a = bc2[c];
#pragma unroll 8
        for (int k = 0; k < 64; ++k) a = fmaf(hid[b * 64 + k], Wc2[k * 10 + c], a);
        out[tid] = a;
    }
}

extern "C" void kernel_launch(void* const* d_in, const int* in_sizes, int n_in, void* d_out, int out_size, void* d_ws,
                              size_t ws_size, hipStream_t stream) {
    const float* x = (const float*)d_in[0];
    const int* ei = (const int*)d_in[1];
    const int* e_src = ei;
    const int* e_dst = ei + E_TOT;
    const float* W0 = (const float*)d_in[2];
    const float* b0 = (const float*)d_in[3];
    const float* W1 = (const float*)d_in[4];
    const float* b1 = (const float*)d_in[5];
    const float* Wm = (const float*)d_in[6];
    const float* bm = (const float*)d_in[7];
    const float* Wih = (const float*)d_in[8];
    const float* Whh = (const float*)d_in[9];
    const float* bih = (const float*)d_in[10];
    const float* bhh = (const float*)d_in[11];
    const float* Wc1 = (const float*)d_in[12];
    const float* bc1 = (const float*)d_in[13];
    const float* Wc2 = (const float*)d_in[14];
    const float* bc2 = (const float*)d_in[15];
    float* out = (float*)d_out;

    char* base = (char*)d_ws;
    size_t off = 0;
    auto alloc = [&](size_t bytes) {
        size_t o = off;
        off = (off + bytes + 255) & ~(size_t)255;
        return o;
    };
    size_t o_gcur = alloc(256 * 4);
    size_t o_row2 = alloc((size_t)NN_TOT * 8);
    size_t o_er = alloc((size_t)NBINS * CAP * 4);      // padded per-bin src-only records
    size_t o_ertmp = alloc((size_t)NBINS * CAP * 8);   // padded per-bin (src,dst) records
    size_t o_xd = alloc((size_t)NN_TOT * 16);
    size_t o_gi = alloc((size_t)(T_SZ + 2) * B_SZ * 384 * 4);  // +2 steps: branchless tail prefetch
    size_t o_wihh = alloc((size_t)384 * 128 * 2);
    size_t o_wihl = alloc((size_t)384 * 128 * 2);
    size_t o_frh = alloc((size_t)B_SZ * T_SZ * 128 * 2);
    size_t o_frl = alloc((size_t)B_SZ * T_SZ * 128 * 2);
    size_t o_w1p = alloc((size_t)128 * 128 * 2);
    size_t o_wmp = alloc((size_t)128 * 128 * 2);
    size_t o_whhp = alloc((size_t)128 * 384 * 2);
    size_t o_w0h = alloc((size_t)384 * 2);
    size_t o_b0h = alloc((size_t)128 * 2);
    size_t o_ht = alloc((size_t)B_SZ * 128 * 4);
    size_t o_z0 = alloc((size_t)NN_TOT * 16);
    size_t o_h1 = alloc((size_t)NN_TOT * HID * 2);
    if (off > ws_size) return;

    int* gcur = (int*)(base + o_gcur);
    int2* row2 = (int2*)(base + o_row2);
    int* er = (int*)(base + o_er);
    int2* er_tmp = (int2*)(base + o_ertmp);
    float4* xd = (float4*)(base + o_xd);
    float* GIt = (float*)(base + o_gi);
    _Float16* Wihh = (_Float16*)(base + o_wihh);
    _Float16* Wihl = (_Float16*)(base + o_wihl);
    _Float16* FRh = (_Float16*)(base + o_frh);
    _Float16* FRl = (_Float16*)(base + o_frl);
    _Float16* W1p = (_Float16*)(base + o_w1p);
    _Float16* Wmp = (_Float16*)(base + o_wmp);
    _Float16* Whhp = (_Float16*)(base + o_whhp);
    _Float16* W0h = (_Float16*)(base + o_w0h);
    _Float16* b0h = (_Float16*)(base + o_b0h);
    float* hT = (float*)(base + o_ht);
    float4* z0 = (float4*)(base + o_z0);
    _Float16* h1 = (_Float16*)(base + o_h1);

    hipMemsetAsync(base + o_gcur, 0, 256 * 4, stream);  // zero-seeded bin cursors

    k_scatter<<<NSB + 192, 256, 0, stream>>>(e_src, e_dst, gcur, er_tmp,
                                             Wih, Whh, W1, Wm, W0, b0,
                                             Wihh, Wihl, W1p, Wmp, Whhp, W0h, b0h);
    k_binsort2<<<NBINS, 256, 0, stream>>>(er_tmp, gcur, x, er, row2, xd);
    k_z0<<<NN_TOT / 64, 256, 0, stream>>>(xd, row2, er, z0);
    k_agg_mm<<<NN_TOT / 64, 256, 0, stream>>>(z0, row2, er, W0h, b0h, W1p, b1, h1);
    k_mm_pool<<<B_SZ * T_SZ, 256, 0, stream>>>(h1, Wmp, bm, FRh, FRl);
    k_gi<<<B_SZ * T_SZ / 64, 256, 0, stream>>>(FRh, FRl, Wihh, Wihl, bih, bhh, GIt);
    k_gru<<<4, 512, 0, stream>>>(GIt, Whhp, bhh, hT);
    k_cls<<<1, 384, 0, stream>>>(hT, Wc1, bc1, Wc2, bc2, out);
}

// Round 7
// 377.516 us; speedup vs baseline: 1.1826x; 1.0268x over previous
//
#include <hip/hip_runtime.h>

#define NN_TOT 208896      // 32*96*68 nodes
#define E_TOT  1671168     // NN_TOT*8 edges
#define B_SZ   32
#define T_SZ   96
#define NPF    68          // nodes per frame
#define HID    128
#define NBINS  204         // 208896 / 1024 nodes per bin
#define CAP    9216        // padded per-bin capacity: mean 8192 + 11 sigma (overflow p ~ 1e-27)
#define NSB    816         // scatter blocks = E_TOT / 2048

typedef _Float16 f16x8 __attribute__((ext_vector_type(8)));
typedef _Float16 f16x2v __attribute__((ext_vector_type(2)));
typedef float f32x4 __attribute__((ext_vector_type(4)));

// ---------------- single-pass scatter into padded bins (+ fused weight prep blocks) ----------------
// Edge records packed to 4B: src (18b) | local-dst (10b) << 18. Blocks [0,816): LDS-hist scatter
// into er_tmp[bin*CAP + cursor] (gcur zero-seeded). Blocks [816,1008): weight prep.
__global__ __launch_bounds__(256) void k_scatter(const int* __restrict__ src, const int* __restrict__ dst,
                                                 int* __restrict__ gcur, int* __restrict__ er_tmp,
                                                 const float* __restrict__ Wih, const float* __restrict__ Whh,
                                                 const float* __restrict__ W1, const float* __restrict__ Wm,
                                                 const float* __restrict__ W0, const float* __restrict__ b0,
                                                 _Float16* __restrict__ Wihh, _Float16* __restrict__ Wihl,
                                                 _Float16* __restrict__ W1p, _Float16* __restrict__ Wmp,
                                                 _Float16* __restrict__ Whhp, _Float16* __restrict__ W0h,
                                                 _Float16* __restrict__ b0h) {
    const int bid = blockIdx.x;
    const int tid = threadIdx.x;
    if (bid >= NSB) {
        // ---- weight prep (uniform per-block branch) ----
        int i = (bid - NSB) * 256 + tid;  // 0..49151
        {
            // Wih split-f16 frag pack: B[k][o] = Wih[o][k]; f = j*4+kk, j=0..23 (N=384)
            int e = i & 7;
            int lane = (i >> 3) & 63;
            int f = i >> 9;  // 0..95
            int j = f >> 2, kk = f & 3;
            int q = lane >> 4, p = lane & 15;
            float wv = Wih[(size_t)(j * 16 + p) * 128 + kk * 32 + q * 8 + e];
            _Float16 hi = (_Float16)wv;
            Wihh[i] = hi;
            Wihl[i] = (_Float16)(wv - (float)hi);
        }
        {
            // Whh frag pack: i = (f*64 + lane)*8 + e, f = (wv*3+g)*4+kk
            int e = i & 7;
            int lane = (i >> 3) & 63;
            int f = i >> 9;  // 0..95
            int kk = f & 3, g = (f >> 2) % 3, wv = f / 12;
            int q = lane >> 4, c = lane & 15;
            Whhp[i] = (_Float16)Whh[(size_t)(g * 128 + 16 * wv + c) * 128 + kk * 32 + q * 8 + e];
        }
        if (i < 16384) {
            int f = i >> 9;          // frag id 0..31
            int j = f >> 2, kk = f & 3;
            int lane = (i >> 3) & 63;
            int e = i & 7;
            int q = lane >> 4, p = lane & 15;
            int k = kk * 32 + q * 8 + e, n = j * 16 + p;
            W1p[i] = (_Float16)W1[k * 128 + n];
            Wmp[i] = (_Float16)Wm[k * 128 + n];
        }
        if (i < 384) W0h[i] = (_Float16)W0[i];
        if (i < 128) b0h[i] = (_Float16)b0[i];
        return;
    }
    __shared__ int hist[NBINS];
    __shared__ int lbase[NBINS];
    for (int i = tid; i < NBINS; i += 256) hist[i] = 0;
    __syncthreads();
    const int be = bid * 2048 + tid * 8;
    int s[8], d[8], rk[8];
    *(int4*)&s[0] = *(const int4*)&src[be];
    *(int4*)&s[4] = *(const int4*)&src[be + 4];
    *(int4*)&d[0] = *(const int4*)&dst[be];
    *(int4*)&d[4] = *(const int4*)&dst[be + 4];
#pragma unroll
    for (int j = 0; j < 8; ++j) rk[j] = atomicAdd(&hist[d[j] >> 10], 1);
    __syncthreads();
    for (int i = tid; i < NBINS; i += 256) lbase[i] = atomicAdd(&gcur[i], hist[i]);
    __syncthreads();
#pragma unroll
    for (int j = 0; j < 8; ++j) {
        int b = d[j] >> 10;
        er_tmp[(size_t)b * CAP + lbase[b] + rk[j]] = s[j] | ((d[j] & 1023) << 18);
    }
}

// ---------------- CSR pass C: records register-cached (single global read), LDS count+scan ----
// row2[n] = (beg,end) in padded er coords; xd[i] = (x*is, is) — factorized GCN norm.
__global__ __launch_bounds__(256) void k_binsort2(const int* __restrict__ er_tmp, const int* __restrict__ gcur,
                                                  const float* __restrict__ x, int* __restrict__ er,
                                                  int2* __restrict__ row2, float4* __restrict__ xd) {
    __shared__ int lcnt[1024];
    __shared__ int lofs[1024];
    __shared__ int ts[256];
    const int tid = threadIdx.x;
    const int nb = blockIdx.x << 10;
    const int base0 = blockIdx.x * CAP;
    for (int i = tid; i < 1024; i += 256) lcnt[i] = 0;
    __syncthreads();
    const int nrec = gcur[blockIdx.x];
    // load all bin records once into registers (static unroll -> VGPRs, rule #20)
    int rec[36];  // 36*256 == CAP
#pragma unroll
    for (int j = 0; j < 36; ++j) {
        int idx = tid + j * 256;
        rec[j] = (idx < nrec) ? er_tmp[base0 + idx] : -1;
    }
#pragma unroll
    for (int j = 0; j < 36; ++j)
        if (rec[j] >= 0) atomicAdd(&lcnt[rec[j] >> 18], 1);
    __syncthreads();
    const int base = tid * 4;
    const int c0 = lcnt[base], c1 = lcnt[base + 1], c2 = lcnt[base + 2], c3 = lcnt[base + 3];
    int ssum = c0 + c1 + c2 + c3;
    ts[tid] = ssum;
    __syncthreads();
    int inc = ssum;
    for (int off = 1; off < 256; off <<= 1) {
        int add = (tid >= off) ? ts[tid - off] : 0;
        __syncthreads();
        inc += add;
        ts[tid] = inc;
        __syncthreads();
    }
    const int b0 = base0 + (inc - ssum);  // padded-coord exclusive offset of node base
    lofs[base] = b0;
    lofs[base + 1] = b0 + c0;
    lofs[base + 2] = b0 + c0 + c1;
    lofs[base + 3] = b0 + c0 + c1 + c2;
    row2[nb + base] = make_int2(b0, b0 + c0);
    row2[nb + base + 1] = make_int2(b0 + c0, b0 + c0 + c1);
    row2[nb + base + 2] = make_int2(b0 + c0 + c1, b0 + c0 + c1 + c2);
    row2[nb + base + 3] = make_int2(b0 + c0 + c1 + c2, b0 + ssum);
    // xd pack: 12 contiguous floats = 3 float4 per thread (48B aligned)
    {
        const float4* xv = (const float4*)(x + 3 * (size_t)(nb + base));
        float4 a = xv[0], b = xv[1], c = xv[2];
        float i0 = 1.0f / sqrtf(1.f + (float)c0);
        float i1 = 1.0f / sqrtf(1.f + (float)c1);
        float i2 = 1.0f / sqrtf(1.f + (float)c2);
        float i3 = 1.0f / sqrtf(1.f + (float)c3);
        xd[nb + base + 0] = make_float4(a.x * i0, a.y * i0, a.z * i0, i0);
        xd[nb + base + 1] = make_float4(a.w * i1, b.x * i1, b.y * i1, i1);
        xd[nb + base + 2] = make_float4(b.z * i2, b.w * i2, c.x * i2, i2);
        xd[nb + base + 3] = make_float4(c.y * i3, c.z * i3, c.w * i3, i3);
    }
    __syncthreads();
#pragma unroll
    for (int j = 0; j < 36; ++j)
        if (rec[j] >= 0) {
            int p = atomicAdd(&lofs[rec[j] >> 18], 1);
            er[p] = rec[j] & 0x3FFFF;  // src only: norm factorized via xd/z0.w
        }
}

// ---------------- z0: 3-dim GCN0 aggregate, factorized norm ----------------
__global__ __launch_bounds__(256) void k_z0(const float4* __restrict__ xd, const int2* __restrict__ row2,
                                            const int* __restrict__ er, float4* __restrict__ z0out) {
    const int tid = threadIdx.x;
    const int blk = blockIdx.x;
    const int li = tid >> 2;
    const int slot = tid & 3;
    const int n = blk * 64 + li;
    const int2 be2 = row2[n];
    float p0 = 0.f, p1 = 0.f, p2 = 0.f;
    for (int ei = be2.x + slot; ei < be2.y; ei += 4) {
        float4 f = xd[er[ei]];
        p0 += f.x;
        p1 += f.y;
        p2 += f.z;
    }
    p0 += __shfl_xor(p0, 1); p1 += __shfl_xor(p1, 1); p2 += __shfl_xor(p2, 1);
    p0 += __shfl_xor(p0, 2); p1 += __shfl_xor(p1, 2); p2 += __shfl_xor(p2, 2);
    if (slot == 0) {
        const float4 own = xd[n];
        const float w = own.w;
        float4 z;
        z.x = w * (p0 + own.x);
        z.y = w * (p1 + own.y);
        z.z = w * (p2 + own.z);
        z.w = w;
        z0out[n] = z;
    }
}

// ---------------- fused: aggregation w/ packed-f16 h0 recompute + GEMM1 MFMA -> h1 ----------------
__global__ __launch_bounds__(256, 4) void k_agg_mm(const float4* __restrict__ z0, const int2* __restrict__ row2,
                                                   const int* __restrict__ er, const _Float16* __restrict__ W0h,
                                                   const _Float16* __restrict__ b0h, const _Float16* __restrict__ W1p,
                                                   const float* __restrict__ b1, _Float16* __restrict__ h1) {
    __shared__ __align__(16) _Float16 As[64 * 136];
    const int tid = threadIdx.x;
    const int w = tid >> 6, lane = tid & 63;
    const int blk = blockIdx.x;

    {
        const int node = blk * 64 + lane;
        const int2 be2 = row2[node];
        const int beg = be2.x, end = be2.y;
        const f16x2v* __restrict__ W0p = (const f16x2v*)W0h;
        const f16x2v* __restrict__ b0p = (const f16x2v*)b0h;
        const int pb = w * 16;
        const f16x2v zero2 = {(_Float16)0.f, (_Float16)0.f};
        f16x2v w0p[16], w1p[16], w2p[16], bbp[16];
#pragma unroll
        for (int j = 0; j < 16; ++j) {
            w0p[j] = W0p[pb + j];
            w1p[j] = W0p[64 + pb + j];
            w2p[j] = W0p[128 + pb + j];
            bbp[j] = b0p[pb + j];
        }
        const float4 zs = z0[node];
        const _Float16 isd = (_Float16)zs.w;
        const f16x2v dnn = {isd, isd};
        f16x2v accp[16];
        {
            _Float16 sx = (_Float16)zs.x, sy = (_Float16)zs.y, sz = (_Float16)zs.z;
            f16x2v zxx = {sx, sx}, zyy = {sy, sy}, zzz = {sz, sz};
#pragma unroll
            for (int j = 0; j < 16; ++j) {
                f16x2v t = zxx * w0p[j] + (zyy * w1p[j] + (zzz * w2p[j] + bbp[j]));
                t = __builtin_elementwise_max(t, zero2);
                accp[j] = t * dnn;
            }
        }
        int ei = beg;
        for (; ei + 2 <= end; ei += 2) {
            int sa = er[ei], sb = er[ei + 1];
            float4 za = z0[sa];
            float4 zb = z0[sb];
            _Float16 ax = (_Float16)za.x, ay = (_Float16)za.y, az = (_Float16)za.z;
            _Float16 aen = (_Float16)za.w;
            _Float16 bx = (_Float16)zb.x, by = (_Float16)zb.y, bz = (_Float16)zb.z;
            _Float16 ben = (_Float16)zb.w;
            f16x2v axx = {ax, ax}, ayy = {ay, ay}, azz = {az, az}, aee = {aen, aen};
            f16x2v bxx = {bx, bx}, byy = {by, by}, bzz = {bz, bz}, bee = {ben, ben};
#pragma unroll
            for (int j = 0; j < 16; ++j) {
                f16x2v t = axx * w0p[j] + (ayy * w1p[j] + (azz * w2p[j] + bbp[j]));
                t = __builtin_elementwise_max(t, zero2);
                accp[j] = t * aee + accp[j];
            }
#pragma unroll
            for (int j = 0; j < 16; ++j) {
                f16x2v t = bxx * w0p[j] + (byy * w1p[j] + (bzz * w2p[j] + bbp[j]));
                t = __builtin_elementwise_max(t, zero2);
                accp[j] = t * bee + accp[j];
            }
        }
        if (ei < end) {
            float4 za = z0[er[ei]];
            _Float16 ax = (_Float16)za.x, ay = (_Float16)za.y, az = (_Float16)za.z;
            _Float16 aen = (_Float16)za.w;
            f16x2v axx = {ax, ax}, ayy = {ay, ay}, azz = {az, az}, aee = {aen, aen};
#pragma unroll
            for (int j = 0; j < 16; ++j) {
                f16x2v t = axx * w0p[j] + (ayy * w1p[j] + (azz * w2p[j] + bbp[j]));
                t = __builtin_elementwise_max(t, zero2);
                accp[j] = t * aee + accp[j];
            }
        }
        _Float16* dst = &As[lane * 136 + w * 32];
#pragma unroll
        for (int j = 0; j < 16; ++j) *(f16x2v*)(dst + 2 * j) = accp[j] * dnn;
    }
    __syncthreads();

    const int q = lane >> 4, c = lane & 15;
    f16x8 afr[4];
#pragma unroll
    for (int kk = 0; kk < 4; ++kk) afr[kk] = *(const f16x8*)(&As[(w * 16 + c) * 136 + kk * 32 + q * 8]);
    const f16x8* __restrict__ Bv = (const f16x8*)W1p;
    _Float16* Cst = &As[w * 2176];
#pragma unroll
    for (int j = 0; j < 8; ++j) {
        f32x4 cc = {0.f, 0.f, 0.f, 0.f};
#pragma unroll
        for (int kk = 0; kk < 4; ++kk)
            cc = __builtin_amdgcn_mfma_f32_16x16x32_f16(afr[kk], Bv[(j * 4 + kk) * 64 + lane], cc, 0, 0, 0);
        const float bi = b1[j * 16 + c];
#pragma unroll
        for (int r = 0; r < 4; ++r) Cst[(q * 4 + r) * 128 + j * 16 + c] = (_Float16)fmaxf(cc[r] + bi, 0.f);
    }
#pragma unroll
    for (int it = 0; it < 4; ++it) {
        int idx = it * 64 + lane;
        *(f16x8*)(h1 + (size_t)(blk * 64 + w * 16) * 128 + idx * 8) = *(const f16x8*)(&As[w * 2176 + idx * 8]);
    }
}

// ---------------- fused: GEMM2 (f16 MFMA) + relu + frame mean -> FR (split f16) ----
__global__ __launch_bounds__(256) void k_mm_pool(const _Float16* __restrict__ h1, const _Float16* __restrict__ Wmp,
                                                 const float* __restrict__ bm, _Float16* __restrict__ FRh,
                                                 _Float16* __restrict__ FRl) {
    __shared__ __align__(16) _Float16 As[80 * 136];
    __shared__ float colpart[4 * 128];
    const int tid = threadIdx.x;
    const int w = tid >> 6, lane = tid & 63;
    const int q = lane >> 4, c = lane & 15;
    const int bt = blockIdx.x;

    const f16x8* __restrict__ srcv = (const f16x8*)(h1 + (size_t)bt * NPF * HID);
    for (int idx = tid; idx < 80 * 17; idx += 256) {
        int row = idx / 17, ch = idx % 17;
        f16x8 v;
        if (row < NPF && ch < 16) {
            v = srcv[row * 16 + ch];
        } else {
#pragma unroll
            for (int k = 0; k < 8; ++k) v[k] = (_Float16)0.f;
        }
        *(f16x8*)(&As[row * 136 + ch * 8]) = v;
    }
    __syncthreads();

    const f16x8* __restrict__ Bv = (const f16x8*)Wmp;
    const int npass = (w == 0) ? 2 : 1;
    for (int pass = 0; pass < npass; ++pass) {
        const int mt = pass ? 4 : w;
        f16x8 afr[4];
#pragma unroll
        for (int kk = 0; kk < 4; ++kk) afr[kk] = *(const f16x8*)(&As[(mt * 16 + c) * 136 + kk * 32 + q * 8]);
#pragma unroll
        for (int j = 0; j < 8; ++j) {
            f32x4 cc = {0.f, 0.f, 0.f, 0.f};
#pragma unroll
            for (int kk = 0; kk < 4; ++kk)
                cc = __builtin_amdgcn_mfma_f32_16x16x32_f16(afr[kk], Bv[(j * 4 + kk) * 64 + lane], cc, 0, 0, 0);
            const float bi = bm[j * 16 + c];
            float s = 0.f;
#pragma unroll
            for (int r = 0; r < 4; ++r) {
                int m = mt * 16 + q * 4 + r;
                float v = fmaxf(cc[r] + bi, 0.f);
                s += (m < NPF) ? v : 0.f;
            }
            s += __shfl_xor(s, 16);
            s += __shfl_xor(s, 32);
            if (lane < 16) {
                float* dst = &colpart[w * 128 + j * 16 + c];
                *dst = (pass == 0) ? s : (*dst + s);
            }
        }
    }
    __syncthreads();
    if (tid < 128) {
        float v = (colpart[tid] + colpart[128 + tid] + colpart[256 + tid] + colpart[384 + tid]) * (1.0f / NPF);
        _Float16 hi = (_Float16)v;
        FRh[(size_t)blockIdx.x * 128 + tid] = hi;
        FRl[(size_t)blockIdx.x * 128 + tid] = (_Float16)(v - (float)hi);
    }
}

// ---------------- gi GEMM: FR[3072x128] @ Wih^T -> GIt (time-major, folded) ----
__global__ __launch_bounds__(256) void k_gi(const _Float16* __restrict__ FRh, const _Float16* __restrict__ FRl,
                                            const _Float16* __restrict__ Wihh, const _Float16* __restrict__ Wihl,
                                            const float* __restrict__ bih, const float* __restrict__ bhh,
                                            float* __restrict__ GIt) {
    __shared__ __align__(16) _Float16 Ah[64 * 136];
    __shared__ __align__(16) _Float16 Al[64 * 136];
    const int tid = threadIdx.x;
    const int w = tid >> 6, lane = tid & 63;
    const int q = lane >> 4, p = lane & 15;
    const int nb = blockIdx.x * 64;

    const f16x8* __restrict__ sh = (const f16x8*)(FRh + (size_t)nb * 128);
    const f16x8* __restrict__ sl = (const f16x8*)(FRl + (size_t)nb * 128);
    for (int idx = tid; idx < 64 * 16; idx += 256) {
        int row = idx >> 4, ch = idx & 15;
        *(f16x8*)(&Ah[row * 136 + ch * 8]) = sh[idx];
        *(f16x8*)(&Al[row * 136 + ch * 8]) = sl[idx];
    }
    __syncthreads();

    f16x8 ah[4], al[4];
#pragma unroll
    for (int kk = 0; kk < 4; ++kk) {
        ah[kk] = *(const f16x8*)(&Ah[(w * 16 + p) * 136 + kk * 32 + q * 8]);
        al[kk] = *(const f16x8*)(&Al[(w * 16 + p) * 136 + kk * 32 + q * 8]);
    }
    const f16x8* __restrict__ Bh = (const f16x8*)Wihh;
    const f16x8* __restrict__ Bl = (const f16x8*)Wihl;
    int dr[4];
#pragma unroll
    for (int r = 0; r < 4; ++r) {
        int m = nb + w * 16 + q * 4 + r;
        int bb = m / 96, tt = m - bb * 96;
        dr[r] = (tt * B_SZ + bb) * 384;
    }
#pragma unroll
    for (int j = 0; j < 24; ++j) {
        f32x4 cc = {0.f, 0.f, 0.f, 0.f};
#pragma unroll
        for (int kk = 0; kk < 4; ++kk)
            cc = __builtin_amdgcn_mfma_f32_16x16x32_f16(ah[kk], Bh[(j * 4 + kk) * 64 + lane], cc, 0, 0, 0);
#pragma unroll
        for (int kk = 0; kk < 4; ++kk)
            cc = __builtin_amdgcn_mfma_f32_16x16x32_f16(ah[kk], Bl[(j * 4 + kk) * 64 + lane], cc, 0, 0, 0);
#pragma unroll
        for (int kk = 0; kk < 4; ++kk)
            cc = __builtin_amdgcn_mfma_f32_16x16x32_f16(al[kk], Bh[(j * 4 + kk) * 64 + lane], cc, 0, 0, 0);
        const int o = j * 16 + p;
        const float bias = bih[o] + ((o < 256) ? bhh[o] : 0.f);
        const float scale = (o < 256) ? -1.44269504f : 1.f;
#pragma unroll
        for (int r = 0; r < 4; ++r) GIt[dr[r] + o] = (cc[r] + bias) * scale;
    }
}

// ---------------- GRU recurrence (+ fused classifier via last-block ticket) ------
#define GRU_SYNC()                                              \
    asm volatile("s_waitcnt lgkmcnt(0)" ::: "memory");          \
    __builtin_amdgcn_s_barrier();                               \
    __builtin_amdgcn_sched_barrier(0);

#define GRU_BODY(PAR, GU, GL, JOFF)                                                                  \
    {                                                                                                \
        const _Float16* rb = hbuf[PAR];                                                              \
        _Float16* wb = hbuf[PAR ^ 1];                                                                \
        f16x8 afr[4];                                                                                \
        _Pragma("unroll") for (int kk = 0; kk < 4; ++kk)                                             \
            afr[kk] = *(const f16x8*)(&rb[c * 144 + kk * 32 + q * 8]);                               \
        const float* lp = pb + (size_t)(JOFF + 2) * STRIDE;                                          \
        _Pragma("unroll") for (int r = 0; r < 4; ++r)                                                \
            _Pragma("unroll") for (int g = 0; g < 3; ++g)                                            \
                GL[r * 3 + g] = lp[r * 384 + g * 128];                                               \
        f32x4 cc[3];                                                                                 \
        _Pragma("unroll") for (int g = 0; g < 3; ++g) {                                              \
            f32x4 a = {0.f, 0.f, 0.f, 0.f};                                                          \
            _Pragma("unroll") for (int kk = 0; kk < 4; ++kk)                                         \
                a = __builtin_amdgcn_mfma_f32_16x16x32_f16(afr[kk], bfr[g][kk], a, 0, 0, 0);         \
            cc[g] = a;                                                                               \
        }                                                                                            \
        _Pragma("unroll") for (int r = 0; r < 4; ++r) {                                              \
            float hn = cc[2][r] + bh2;                                                               \
            float rg = __builtin_amdgcn_rcpf(1.f + exp2f(fmaf(mL2E, cc[0][r], GU[r * 3 + 0])));      \
            float zg = __builtin_amdgcn_rcpf(1.f + exp2f(fmaf(mL2E, cc[1][r], GU[r * 3 + 1])));      \
            float arg = fmaf(rg, hn, GU[r * 3 + 2]);                                                 \
            float u = __builtin_amdgcn_rcpf(exp2f(2.f * L2E * arg) + 1.f);                           \
            float nn = fmaf(-2.f, u, 1.f);                                                           \
            h[r] = fmaf(zg, h[r] - nn, nn);                                                          \
            if (q < 2) wb[(q * 4 + r) * 144 + 16 * w + c] = (_Float16)h[r];                          \
        }                                                                                            \
        GRU_SYNC()                                                                                   \
    }

__global__ __launch_bounds__(512) __attribute__((amdgpu_waves_per_eu(1, 2)))
void k_gru(const float* __restrict__ GIt, const _Float16* __restrict__ Whhp,
           const float* __restrict__ bhh, float* __restrict__ hT,
           const float* __restrict__ Wc1, const float* __restrict__ bc1,
           const float* __restrict__ Wc2, const float* __restrict__ bc2,
           float* __restrict__ out, int* __restrict__ ticket) {
    __shared__ __align__(16) _Float16 hbuf[2][16 * 144];
    __shared__ int tick;
    const int tid = threadIdx.x;
    const int w = tid >> 6, lane = tid & 63;
    const int q = lane >> 4, c = lane & 15;
    const int B = blockIdx.x;  // batches 8B..8B+7
    const float L2E = 1.44269504f;
    const float mL2E = -1.44269504f;
    const int STRIDE = B_SZ * 384;

    f16x8 bfr[3][4];
#pragma unroll
    for (int g = 0; g < 3; ++g)
#pragma unroll
        for (int kk = 0; kk < 4; ++kk)
            bfr[g][kk] = *(const f16x8*)(Whhp + (size_t)(((w * 3 + g) * 4 + kk) * 64 + lane) * 8);
    const float bh2 = bhh[256 + 16 * w + c];
    for (int i = tid; i < 2 * 16 * 144 / 2; i += 512) ((unsigned int*)hbuf)[i] = 0u;
    float h[4] = {0.f, 0.f, 0.f, 0.f};

    const int qq = (q < 2) ? q : 1;
    const float* pb = GIt + (size_t)(B * 8 + qq * 4) * 384 + 16 * w + c;
    float g0[12], g1[12], g2[12];
#pragma unroll
    for (int r = 0; r < 4; ++r)
#pragma unroll
        for (int g = 0; g < 3; ++g) {
            g0[r * 3 + g] = pb[r * 384 + g * 128];
            g1[r * 3 + g] = pb[STRIDE + r * 384 + g * 128];
        }
    GRU_SYNC()

    for (int it = 0; it < T_SZ / 6; ++it) {
        GRU_BODY(0, g0, g2, 0)
        GRU_BODY(1, g1, g0, 1)
        GRU_BODY(0, g2, g1, 2)
        GRU_BODY(1, g0, g2, 3)
        GRU_BODY(0, g1, g0, 4)
        GRU_BODY(1, g2, g1, 5)
        pb += 6 * (size_t)STRIDE;
    }
    if (q < 2) {
#pragma unroll
        for (int r = 0; r < 4; ++r) hT[(size_t)(B * 8 + q * 4 + r) * 128 + 16 * w + c] = h[r];
    }

    // ---- fused classifier: last-finishing block runs it (device-scope ticket + fences) ----
    __syncthreads();
    __threadfence();          // release this block's hT stores device-wide
    __syncthreads();
    if (tid == 0) tick = atomicAdd(ticket, 1);
    __syncthreads();
    if (tick == 3) {
        __threadfence();      // acquire: other blocks' hT stores
        float* hid = (float*)hbuf;  // 2048 floats = 8KB <= 9216B
        for (int idx = tid; idx < 2048; idx += 512) {
            int b = idx >> 6, j = idx & 63;
            float a = bc1[j];
#pragma unroll 8
            for (int k = 0; k < 128; ++k) a = fmaf(hT[b * 128 + k], Wc1[k * 64 + j], a);
            hid[idx] = fmaxf(a, 0.f);
        }
        __syncthreads();
        if (tid < 320) {
            int b = tid / 10, cc2 = tid % 10;
            float a = bc2[cc2];
#pragma unroll 8
            for (int k = 0; k < 64; ++k) a = fmaf(hid[b * 64 + k], Wc2[k * 10 + cc2], a);
            out[tid] = a;
        }
    }
}

extern "C" void kernel_launch(void* const* d_in, const int* in_sizes, int n_in, void* d_out, int out_size, void* d_ws,
                              size_t ws_size, hipStream_t stream) {
    const float* x = (const float*)d_in[0];
    const int* ei = (const int*)d_in[1];
    const int* e_src = ei;
    const int* e_dst = ei + E_TOT;
    const float* W0 = (const float*)d_in[2];
    const float* b0 = (const float*)d_in[3];
    const float* W1 = (const float*)d_in[4];
    const float* b1 = (const float*)d_in[5];
    const float* Wm = (const float*)d_in[6];
    const float* bm = (const float*)d_in[7];
    const float* Wih = (const float*)d_in[8];
    const float* Whh = (const float*)d_in[9];
    const float* bih = (const float*)d_in[10];
    const float* bhh = (const float*)d_in[11];
    const float* Wc1 = (const float*)d_in[12];
    const float* bc1 = (const float*)d_in[13];
    const float* Wc2 = (const float*)d_in[14];
    const float* bc2 = (const float*)d_in[15];
    float* out = (float*)d_out;

    char* base = (char*)d_ws;
    size_t off = 0;
    auto alloc = [&](size_t bytes) {
        size_t o = off;
        off = (off + bytes + 255) & ~(size_t)255;
        return o;
    };
    size_t o_gcur = alloc(256 * 4);                    // bins 0..203 + ticket at [255]
    size_t o_row2 = alloc((size_t)NN_TOT * 8);
    size_t o_er = alloc((size_t)NBINS * CAP * 4);      // padded per-bin src-only records
    size_t o_ertmp = alloc((size_t)NBINS * CAP * 4);   // padded per-bin packed (src|ldst<<18)
    size_t o_xd = alloc((size_t)NN_TOT * 16);
    size_t o_gi = alloc((size_t)(T_SZ + 2) * B_SZ * 384 * 4);  // +2 steps: branchless tail prefetch
    size_t o_wihh = alloc((size_t)384 * 128 * 2);
    size_t o_wihl = alloc((size_t)384 * 128 * 2);
    size_t o_frh = alloc((size_t)B_SZ * T_SZ * 128 * 2);
    size_t o_frl = alloc((size_t)B_SZ * T_SZ * 128 * 2);
    size_t o_w1p = alloc((size_t)128 * 128 * 2);
    size_t o_wmp = alloc((size_t)128 * 128 * 2);
    size_t o_whhp = alloc((size_t)128 * 384 * 2);
    size_t o_w0h = alloc((size_t)384 * 2);
    size_t o_b0h = alloc((size_t)128 * 2);
    size_t o_ht = alloc((size_t)B_SZ * 128 * 4);
    size_t o_z0 = alloc((size_t)NN_TOT * 16);
    size_t o_h1 = alloc((size_t)NN_TOT * HID * 2);
    if (off > ws_size) return;

    int* gcur = (int*)(base + o_gcur);
    int* ticket = gcur + 255;
    int2* row2 = (int2*)(base + o_row2);
    int* er = (int*)(base + o_er);
    int* er_tmp = (int*)(base + o_ertmp);
    float4* xd = (float4*)(base + o_xd);
    float* GIt = (float*)(base + o_gi);
    _Float16* Wihh = (_Float16*)(base + o_wihh);
    _Float16* Wihl = (_Float16*)(base + o_wihl);
    _Float16* FRh = (_Float16*)(base + o_frh);
    _Float16* FRl = (_Float16*)(base + o_frl);
    _Float16* W1p = (_Float16*)(base + o_w1p);
    _Float16* Wmp = (_Float16*)(base + o_wmp);
    _Float16* Whhp = (_Float16*)(base + o_whhp);
    _Float16* W0h = (_Float16*)(base + o_w0h);
    _Float16* b0h = (_Float16*)(base + o_b0h);
    float* hT = (float*)(base + o_ht);
    float4* z0 = (float4*)(base + o_z0);
    _Float16* h1 = (_Float16*)(base + o_h1);

    hipMemsetAsync(base + o_gcur, 0, 256 * 4, stream);  // bin cursors + cls ticket

    k_scatter<<<NSB + 192, 256, 0, stream>>>(e_src, e_dst, gcur, er_tmp,
                                             Wih, Whh, W1, Wm, W0, b0,
                                             Wihh, Wihl, W1p, Wmp, Whhp, W0h, b0h);
    k_binsort2<<<NBINS, 256, 0, stream>>>(er_tmp, gcur, x, er, row2, xd);
    k_z0<<<NN_TOT / 64, 256, 0, stream>>>(xd, row2, er, z0);
    k_agg_mm<<<NN_TOT / 64, 256, 0, stream>>>(z0, row2, er, W0h, b0h, W1p, b1, h1);
    k_mm_pool<<<B_SZ * T_SZ, 256, 0, stream>>>(h1, Wmp, bm, FRh, FRl);
    k_gi<<<B_SZ * T_SZ / 64, 256, 0, stream>>>(FRh, FRl, Wihh, Wihl, bih, bhh, GIt);
    k_gru<<<4, 512, 0, stream>>>(GIt, Whhp, bhh, hT, Wc1, bc1, Wc2, bc2, out, ticket);
}

// Round 9
// 359.136 us; speedup vs baseline: 1.2431x; 1.0512x over previous
//
#include <hip/hip_runtime.h>

#define NN_TOT 208896      // 32*96*68 nodes
#define E_TOT  1671168     // NN_TOT*8 edges
#define B_SZ   32
#define T_SZ   96
#define NPF    68          // nodes per frame
#define HID    128
#define NBINS  204         // 208896 / 1024 nodes per bin
#define CAP    9216        // padded per-bin capacity: mean 8192 + 11 sigma (overflow p ~ 1e-27)
#define NSB    816         // scatter blocks = E_TOT / 2048

typedef _Float16 f16x8 __attribute__((ext_vector_type(8)));
typedef _Float16 f16x2v __attribute__((ext_vector_type(2)));
typedef float f32x4 __attribute__((ext_vector_type(4)));

// ---------------- single-pass scatter into padded bins (+ fused weight prep blocks) ----------------
// Edge records packed to 4B: src (18b) | local-dst (10b) << 18. Blocks [0,816): LDS-hist scatter
// into er_tmp[bin*CAP + cursor] (gcur zero-seeded). Blocks [816,1008): weight prep.
__global__ __launch_bounds__(256) void k_scatter(const int* __restrict__ src, const int* __restrict__ dst,
                                                 int* __restrict__ gcur, int* __restrict__ er_tmp,
                                                 const float* __restrict__ Wih, const float* __restrict__ Whh,
                                                 const float* __restrict__ W1, const float* __restrict__ Wm,
                                                 const float* __restrict__ W0, const float* __restrict__ b0,
                                                 _Float16* __restrict__ Wihh, _Float16* __restrict__ Wihl,
                                                 _Float16* __restrict__ W1p, _Float16* __restrict__ Wmp,
                                                 _Float16* __restrict__ Whhp, _Float16* __restrict__ W0h,
                                                 _Float16* __restrict__ b0h) {
    const int bid = blockIdx.x;
    const int tid = threadIdx.x;
    if (bid >= NSB) {
        // ---- weight prep (uniform per-block branch) ----
        int i = (bid - NSB) * 256 + tid;  // 0..49151
        {
            // Wih split-f16 frag pack: B[k][o] = Wih[o][k]; f = j*4+kk, j=0..23 (N=384)
            int e = i & 7;
            int lane = (i >> 3) & 63;
            int f = i >> 9;  // 0..95
            int j = f >> 2, kk = f & 3;
            int q = lane >> 4, p = lane & 15;
            float wv = Wih[(size_t)(j * 16 + p) * 128 + kk * 32 + q * 8 + e];
            _Float16 hi = (_Float16)wv;
            Wihh[i] = hi;
            Wihl[i] = (_Float16)(wv - (float)hi);
        }
        {
            // Whh frag pack: i = (f*64 + lane)*8 + e, f = (wv*3+g)*4+kk
            int e = i & 7;
            int lane = (i >> 3) & 63;
            int f = i >> 9;  // 0..95
            int kk = f & 3, g = (f >> 2) % 3, wv = f / 12;
            int q = lane >> 4, c = lane & 15;
            Whhp[i] = (_Float16)Whh[(size_t)(g * 128 + 16 * wv + c) * 128 + kk * 32 + q * 8 + e];
        }
        if (i < 16384) {
            int f = i >> 9;          // frag id 0..31
            int j = f >> 2, kk = f & 3;
            int lane = (i >> 3) & 63;
            int e = i & 7;
            int q = lane >> 4, p = lane & 15;
            int k = kk * 32 + q * 8 + e, n = j * 16 + p;
            W1p[i] = (_Float16)W1[k * 128 + n];
            Wmp[i] = (_Float16)Wm[k * 128 + n];
        }
        if (i < 384) W0h[i] = (_Float16)W0[i];
        if (i < 128) b0h[i] = (_Float16)b0[i];
        return;
    }
    __shared__ int hist[NBINS];
    __shared__ int lbase[NBINS];
    for (int i = tid; i < NBINS; i += 256) hist[i] = 0;
    __syncthreads();
    const int be = bid * 2048 + tid * 8;
    int s[8], d[8], rk[8];
    *(int4*)&s[0] = *(const int4*)&src[be];
    *(int4*)&s[4] = *(const int4*)&src[be + 4];
    *(int4*)&d[0] = *(const int4*)&dst[be];
    *(int4*)&d[4] = *(const int4*)&dst[be + 4];
#pragma unroll
    for (int j = 0; j < 8; ++j) rk[j] = atomicAdd(&hist[d[j] >> 10], 1);
    __syncthreads();
    for (int i = tid; i < NBINS; i += 256) lbase[i] = atomicAdd(&gcur[i], hist[i]);
    __syncthreads();
#pragma unroll
    for (int j = 0; j < 8; ++j) {
        int b = d[j] >> 10;
        er_tmp[(size_t)b * CAP + lbase[b] + rk[j]] = s[j] | ((d[j] & 1023) << 18);
    }
}

// ---------------- CSR pass C: records register-cached (single global read), LDS count+scan ----
// row2[n] = (beg,end) in padded er coords; xd[i] = (x*is, is) — factorized GCN norm.
__global__ __launch_bounds__(256) void k_binsort2(const int* __restrict__ er_tmp, const int* __restrict__ gcur,
                                                  const float* __restrict__ x, int* __restrict__ er,
                                                  int2* __restrict__ row2, float4* __restrict__ xd) {
    __shared__ int lcnt[1024];
    __shared__ int lofs[1024];
    __shared__ int ts[256];
    const int tid = threadIdx.x;
    const int nb = blockIdx.x << 10;
    const int base0 = blockIdx.x * CAP;
    for (int i = tid; i < 1024; i += 256) lcnt[i] = 0;
    __syncthreads();
    const int nrec = gcur[blockIdx.x];
    // load all bin records once into registers (static unroll -> VGPRs, rule #20)
    int rec[36];  // 36*256 == CAP
#pragma unroll
    for (int j = 0; j < 36; ++j) {
        int idx = tid + j * 256;
        rec[j] = (idx < nrec) ? er_tmp[base0 + idx] : -1;
    }
#pragma unroll
    for (int j = 0; j < 36; ++j)
        if (rec[j] >= 0) atomicAdd(&lcnt[rec[j] >> 18], 1);
    __syncthreads();
    const int base = tid * 4;
    const int c0 = lcnt[base], c1 = lcnt[base + 1], c2 = lcnt[base + 2], c3 = lcnt[base + 3];
    int ssum = c0 + c1 + c2 + c3;
    ts[tid] = ssum;
    __syncthreads();
    int inc = ssum;
    for (int off = 1; off < 256; off <<= 1) {
        int add = (tid >= off) ? ts[tid - off] : 0;
        __syncthreads();
        inc += add;
        ts[tid] = inc;
        __syncthreads();
    }
    const int b0 = base0 + (inc - ssum);  // padded-coord exclusive offset of node base
    lofs[base] = b0;
    lofs[base + 1] = b0 + c0;
    lofs[base + 2] = b0 + c0 + c1;
    lofs[base + 3] = b0 + c0 + c1 + c2;
    row2[nb + base] = make_int2(b0, b0 + c0);
    row2[nb + base + 1] = make_int2(b0 + c0, b0 + c0 + c1);
    row2[nb + base + 2] = make_int2(b0 + c0 + c1, b0 + c0 + c1 + c2);
    row2[nb + base + 3] = make_int2(b0 + c0 + c1 + c2, b0 + ssum);
    // xd pack: 12 contiguous floats = 3 float4 per thread (48B aligned)
    {
        const float4* xv = (const float4*)(x + 3 * (size_t)(nb + base));
        float4 a = xv[0], b = xv[1], c = xv[2];
        float i0 = 1.0f / sqrtf(1.f + (float)c0);
        float i1 = 1.0f / sqrtf(1.f + (float)c1);
        float i2 = 1.0f / sqrtf(1.f + (float)c2);
        float i3 = 1.0f / sqrtf(1.f + (float)c3);
        xd[nb + base + 0] = make_float4(a.x * i0, a.y * i0, a.z * i0, i0);
        xd[nb + base + 1] = make_float4(a.w * i1, b.x * i1, b.y * i1, i1);
        xd[nb + base + 2] = make_float4(b.z * i2, b.w * i2, c.x * i2, i2);
        xd[nb + base + 3] = make_float4(c.y * i3, c.z * i3, c.w * i3, i3);
    }
    __syncthreads();
#pragma unroll
    for (int j = 0; j < 36; ++j)
        if (rec[j] >= 0) {
            int p = atomicAdd(&lofs[rec[j] >> 18], 1);
            er[p] = rec[j] & 0x3FFFF;  // src only: norm factorized via xd/z0.w
        }
}

// ---------------- z0: 3-dim GCN0 aggregate, factorized norm ----------------
__global__ __launch_bounds__(256) void k_z0(const float4* __restrict__ xd, const int2* __restrict__ row2,
                                            const int* __restrict__ er, float4* __restrict__ z0out) {
    const int tid = threadIdx.x;
    const int blk = blockIdx.x;
    const int li = tid >> 2;
    const int slot = tid & 3;
    const int n = blk * 64 + li;
    const int2 be2 = row2[n];
    float p0 = 0.f, p1 = 0.f, p2 = 0.f;
    for (int ei = be2.x + slot; ei < be2.y; ei += 4) {
        float4 f = xd[er[ei]];
        p0 += f.x;
        p1 += f.y;
        p2 += f.z;
    }
    p0 += __shfl_xor(p0, 1); p1 += __shfl_xor(p1, 1); p2 += __shfl_xor(p2, 1);
    p0 += __shfl_xor(p0, 2); p1 += __shfl_xor(p1, 2); p2 += __shfl_xor(p2, 2);
    if (slot == 0) {
        const float4 own = xd[n];
        const float w = own.w;
        float4 z;
        z.x = w * (p0 + own.x);
        z.y = w * (p1 + own.y);
        z.z = w * (p2 + own.z);
        z.w = w;
        z0out[n] = z;
    }
}

// ---------------- fused: aggregation w/ packed-f16 h0 recompute + GEMM1 MFMA -> h1 ----------------
__global__ __launch_bounds__(256, 4) void k_agg_mm(const float4* __restrict__ z0, const int2* __restrict__ row2,
                                                   const int* __restrict__ er, const _Float16* __restrict__ W0h,
                                                   const _Float16* __restrict__ b0h, const _Float16* __restrict__ W1p,
                                                   const float* __restrict__ b1, _Float16* __restrict__ h1) {
    __shared__ __align__(16) _Float16 As[64 * 136];
    const int tid = threadIdx.x;
    const int w = tid >> 6, lane = tid & 63;
    const int blk = blockIdx.x;

    {
        const int node = blk * 64 + lane;
        const int2 be2 = row2[node];
        const int beg = be2.x, end = be2.y;
        const f16x2v* __restrict__ W0p = (const f16x2v*)W0h;
        const f16x2v* __restrict__ b0p = (const f16x2v*)b0h;
        const int pb = w * 16;
        const f16x2v zero2 = {(_Float16)0.f, (_Float16)0.f};
        f16x2v w0p[16], w1p[16], w2p[16], bbp[16];
#pragma unroll
        for (int j = 0; j < 16; ++j) {
            w0p[j] = W0p[pb + j];
            w1p[j] = W0p[64 + pb + j];
            w2p[j] = W0p[128 + pb + j];
            bbp[j] = b0p[pb + j];
        }
        const float4 zs = z0[node];
        const _Float16 isd = (_Float16)zs.w;
        const f16x2v dnn = {isd, isd};
        f16x2v accp[16];
        {
            _Float16 sx = (_Float16)zs.x, sy = (_Float16)zs.y, sz = (_Float16)zs.z;
            f16x2v zxx = {sx, sx}, zyy = {sy, sy}, zzz = {sz, sz};
#pragma unroll
            for (int j = 0; j < 16; ++j) {
                f16x2v t = zxx * w0p[j] + (zyy * w1p[j] + (zzz * w2p[j] + bbp[j]));
                t = __builtin_elementwise_max(t, zero2);
                accp[j] = t * dnn;
            }
        }
        int ei = beg;
        for (; ei + 2 <= end; ei += 2) {
            int sa = er[ei], sb = er[ei + 1];
            float4 za = z0[sa];
            float4 zb = z0[sb];
            _Float16 ax = (_Float16)za.x, ay = (_Float16)za.y, az = (_Float16)za.z;
            _Float16 aen = (_Float16)za.w;
            _Float16 bx = (_Float16)zb.x, by = (_Float16)zb.y, bz = (_Float16)zb.z;
            _Float16 ben = (_Float16)zb.w;
            f16x2v axx = {ax, ax}, ayy = {ay, ay}, azz = {az, az}, aee = {aen, aen};
            f16x2v bxx = {bx, bx}, byy = {by, by}, bzz = {bz, bz}, bee = {ben, ben};
#pragma unroll
            for (int j = 0; j < 16; ++j) {
                f16x2v t = axx * w0p[j] + (ayy * w1p[j] + (azz * w2p[j] + bbp[j]));
                t = __builtin_elementwise_max(t, zero2);
                accp[j] = t * aee + accp[j];
            }
#pragma unroll
            for (int j = 0; j < 16; ++j) {
                f16x2v t = bxx * w0p[j] + (byy * w1p[j] + (bzz * w2p[j] + bbp[j]));
                t = __builtin_elementwise_max(t, zero2);
                accp[j] = t * bee + accp[j];
            }
        }
        if (ei < end) {
            float4 za = z0[er[ei]];
            _Float16 ax = (_Float16)za.x, ay = (_Float16)za.y, az = (_Float16)za.z;
            _Float16 aen = (_Float16)za.w;
            f16x2v axx = {ax, ax}, ayy = {ay, ay}, azz = {az, az}, aee = {aen, aen};
#pragma unroll
            for (int j = 0; j < 16; ++j) {
                f16x2v t = axx * w0p[j] + (ayy * w1p[j] + (azz * w2p[j] + bbp[j]));
                t = __builtin_elementwise_max(t, zero2);
                accp[j] = t * aee + accp[j];
            }
        }
        _Float16* dst = &As[lane * 136 + w * 32];
#pragma unroll
        for (int j = 0; j < 16; ++j) *(f16x2v*)(dst + 2 * j) = accp[j] * dnn;
    }
    __syncthreads();

    const int q = lane >> 4, c = lane & 15;
    f16x8 afr[4];
#pragma unroll
    for (int kk = 0; kk < 4; ++kk) afr[kk] = *(const f16x8*)(&As[(w * 16 + c) * 136 + kk * 32 + q * 8]);
    const f16x8* __restrict__ Bv = (const f16x8*)W1p;
    _Float16* Cst = &As[w * 2176];
#pragma unroll
    for (int j = 0; j < 8; ++j) {
        f32x4 cc = {0.f, 0.f, 0.f, 0.f};
#pragma unroll
        for (int kk = 0; kk < 4; ++kk)
            cc = __builtin_amdgcn_mfma_f32_16x16x32_f16(afr[kk], Bv[(j * 4 + kk) * 64 + lane], cc, 0, 0, 0);
        const float bi = b1[j * 16 + c];
#pragma unroll
        for (int r = 0; r < 4; ++r) Cst[(q * 4 + r) * 128 + j * 16 + c] = (_Float16)fmaxf(cc[r] + bi, 0.f);
    }
#pragma unroll
    for (int it = 0; it < 4; ++it) {
        int idx = it * 64 + lane;
        *(f16x8*)(h1 + (size_t)(blk * 64 + w * 16) * 128 + idx * 8) = *(const f16x8*)(&As[w * 2176 + idx * 8]);
    }
}

// ---------------- fused: GEMM2 (f16 MFMA) + relu + frame mean -> FR (split f16) ----
__global__ __launch_bounds__(256) void k_mm_pool(const _Float16* __restrict__ h1, const _Float16* __restrict__ Wmp,
                                                 const float* __restrict__ bm, _Float16* __restrict__ FRh,
                                                 _Float16* __restrict__ FRl) {
    __shared__ __align__(16) _Float16 As[80 * 136];
    __shared__ float colpart[4 * 128];
    const int tid = threadIdx.x;
    const int w = tid >> 6, lane = tid & 63;
    const int q = lane >> 4, c = lane & 15;
    const int bt = blockIdx.x;

    const f16x8* __restrict__ srcv = (const f16x8*)(h1 + (size_t)bt * NPF * HID);
    for (int idx = tid; idx < 80 * 17; idx += 256) {
        int row = idx / 17, ch = idx % 17;
        f16x8 v;
        if (row < NPF && ch < 16) {
            v = srcv[row * 16 + ch];
        } else {
#pragma unroll
            for (int k = 0; k < 8; ++k) v[k] = (_Float16)0.f;
        }
        *(f16x8*)(&As[row * 136 + ch * 8]) = v;
    }
    __syncthreads();

    const f16x8* __restrict__ Bv = (const f16x8*)Wmp;
    const int npass = (w == 0) ? 2 : 1;
    for (int pass = 0; pass < npass; ++pass) {
        const int mt = pass ? 4 : w;
        f16x8 afr[4];
#pragma unroll
        for (int kk = 0; kk < 4; ++kk) afr[kk] = *(const f16x8*)(&As[(mt * 16 + c) * 136 + kk * 32 + q * 8]);
#pragma unroll
        for (int j = 0; j < 8; ++j) {
            f32x4 cc = {0.f, 0.f, 0.f, 0.f};
#pragma unroll
            for (int kk = 0; kk < 4; ++kk)
                cc = __builtin_amdgcn_mfma_f32_16x16x32_f16(afr[kk], Bv[(j * 4 + kk) * 64 + lane], cc, 0, 0, 0);
            const float bi = bm[j * 16 + c];
            float s = 0.f;
#pragma unroll
            for (int r = 0; r < 4; ++r) {
                int m = mt * 16 + q * 4 + r;
                float v = fmaxf(cc[r] + bi, 0.f);
                s += (m < NPF) ? v : 0.f;
            }
            s += __shfl_xor(s, 16);
            s += __shfl_xor(s, 32);
            if (lane < 16) {
                float* dst = &colpart[w * 128 + j * 16 + c];
                *dst = (pass == 0) ? s : (*dst + s);
            }
        }
    }
    __syncthreads();
    if (tid < 128) {
        float v = (colpart[tid] + colpart[128 + tid] + colpart[256 + tid] + colpart[384 + tid]) * (1.0f / NPF);
        _Float16 hi = (_Float16)v;
        FRh[(size_t)blockIdx.x * 128 + tid] = hi;
        FRl[(size_t)blockIdx.x * 128 + tid] = (_Float16)(v - (float)hi);
    }
}

// ---------------- gi GEMM: FR[3072x128] @ Wih^T -> GIt (time-major, folded) ----
__global__ __launch_bounds__(256) void k_gi(const _Float16* __restrict__ FRh, const _Float16* __restrict__ FRl,
                                            const _Float16* __restrict__ Wihh, const _Float16* __restrict__ Wihl,
                                            const float* __restrict__ bih, const float* __restrict__ bhh,
                                            float* __restrict__ GIt) {
    __shared__ __align__(16) _Float16 Ah[64 * 136];
    __shared__ __align__(16) _Float16 Al[64 * 136];
    const int tid = threadIdx.x;
    const int w = tid >> 6, lane = tid & 63;
    const int q = lane >> 4, p = lane & 15;
    const int nb = blockIdx.x * 64;

    const f16x8* __restrict__ sh = (const f16x8*)(FRh + (size_t)nb * 128);
    const f16x8* __restrict__ sl = (const f16x8*)(FRl + (size_t)nb * 128);
    for (int idx = tid; idx < 64 * 16; idx += 256) {
        int row = idx >> 4, ch = idx & 15;
        *(f16x8*)(&Ah[row * 136 + ch * 8]) = sh[idx];
        *(f16x8*)(&Al[row * 136 + ch * 8]) = sl[idx];
    }
    __syncthreads();

    f16x8 ah[4], al[4];
#pragma unroll
    for (int kk = 0; kk < 4; ++kk) {
        ah[kk] = *(const f16x8*)(&Ah[(w * 16 + p) * 136 + kk * 32 + q * 8]);
        al[kk] = *(const f16x8*)(&Al[(w * 16 + p) * 136 + kk * 32 + q * 8]);
    }
    const f16x8* __restrict__ Bh = (const f16x8*)Wihh;
    const f16x8* __restrict__ Bl = (const f16x8*)Wihl;
    int dr[4];
#pragma unroll
    for (int r = 0; r < 4; ++r) {
        int m = nb + w * 16 + q * 4 + r;
        int bb = m / 96, tt = m - bb * 96;
        dr[r] = (tt * B_SZ + bb) * 384;
    }
#pragma unroll
    for (int j = 0; j < 24; ++j) {
        f32x4 cc = {0.f, 0.f, 0.f, 0.f};
#pragma unroll
        for (int kk = 0; kk < 4; ++kk)
            cc = __builtin_amdgcn_mfma_f32_16x16x32_f16(ah[kk], Bh[(j * 4 + kk) * 64 + lane], cc, 0, 0, 0);
#pragma unroll
        for (int kk = 0; kk < 4; ++kk)
            cc = __builtin_amdgcn_mfma_f32_16x16x32_f16(ah[kk], Bl[(j * 4 + kk) * 64 + lane], cc, 0, 0, 0);
#pragma unroll
        for (int kk = 0; kk < 4; ++kk)
            cc = __builtin_amdgcn_mfma_f32_16x16x32_f16(al[kk], Bh[(j * 4 + kk) * 64 + lane], cc, 0, 0, 0);
        const int o = j * 16 + p;
        const float bias = bih[o] + ((o < 256) ? bhh[o] : 0.f);
        const float scale = (o < 256) ? -1.44269504f : 1.f;
#pragma unroll
        for (int r = 0; r < 4; ++r) GIt[dr[r] + o] = (cc[r] + bias) * scale;
    }
}

// ---------------- GRU recurrence (+ block-local classifier: hT never leaves the block) ------
#define GRU_SYNC()                                              \
    asm volatile("s_waitcnt lgkmcnt(0)" ::: "memory");          \
    __builtin_amdgcn_s_barrier();                               \
    __builtin_amdgcn_sched_barrier(0);

#define GRU_BODY(PAR, GU, GL, JOFF)                                                                  \
    {                                                                                                \
        const _Float16* rb = hbuf[PAR];                                                              \
        _Float16* wb = hbuf[PAR ^ 1];                                                                \
        f16x8 afr[4];                                                                                \
        _Pragma("unroll") for (int kk = 0; kk < 4; ++kk)                                             \
            afr[kk] = *(const f16x8*)(&rb[c * 144 + kk * 32 + q * 8]);                               \
        const float* lp = pb + (size_t)(JOFF + 2) * STRIDE;                                          \
        _Pragma("unroll") for (int r = 0; r < 4; ++r)                                                \
            _Pragma("unroll") for (int g = 0; g < 3; ++g)                                            \
                GL[r * 3 + g] = lp[r * 384 + g * 128];                                               \
        f32x4 cc[3];                                                                                 \
        _Pragma("unroll") for (int g = 0; g < 3; ++g) {                                              \
            f32x4 a = {0.f, 0.f, 0.f, 0.f};                                                          \
            _Pragma("unroll") for (int kk = 0; kk < 4; ++kk)                                         \
                a = __builtin_amdgcn_mfma_f32_16x16x32_f16(afr[kk], bfr[g][kk], a, 0, 0, 0);         \
            cc[g] = a;                                                                               \
        }                                                                                            \
        _Pragma("unroll") for (int r = 0; r < 4; ++r) {                                              \
            float hn = cc[2][r] + bh2;                                                               \
            float rg = __builtin_amdgcn_rcpf(1.f + exp2f(fmaf(mL2E, cc[0][r], GU[r * 3 + 0])));      \
            float zg = __builtin_amdgcn_rcpf(1.f + exp2f(fmaf(mL2E, cc[1][r], GU[r * 3 + 1])));      \
            float arg = fmaf(rg, hn, GU[r * 3 + 2]);                                                 \
            float u = __builtin_amdgcn_rcpf(exp2f(2.f * L2E * arg) + 1.f);                           \
            float nn = fmaf(-2.f, u, 1.f);                                                           \
            h[r] = fmaf(zg, h[r] - nn, nn);                                                          \
            if (q < 2) wb[(q * 4 + r) * 144 + 16 * w + c] = (_Float16)h[r];                          \
        }                                                                                            \
        GRU_SYNC()                                                                                   \
    }

__global__ __launch_bounds__(512) __attribute__((amdgpu_waves_per_eu(1, 2)))
void k_gru(const float* __restrict__ GIt, const _Float16* __restrict__ Whhp,
           const float* __restrict__ bhh,
           const float* __restrict__ Wc1, const float* __restrict__ bc1,
           const float* __restrict__ Wc2, const float* __restrict__ bc2,
           float* __restrict__ out) {
    __shared__ __align__(16) _Float16 hbuf[2][16 * 144];
    const int tid = threadIdx.x;
    const int w = tid >> 6, lane = tid & 63;
    const int q = lane >> 4, c = lane & 15;
    const int B = blockIdx.x;  // batches 8B..8B+7
    const float L2E = 1.44269504f;
    const float mL2E = -1.44269504f;
    const int STRIDE = B_SZ * 384;

    f16x8 bfr[3][4];
#pragma unroll
    for (int g = 0; g < 3; ++g)
#pragma unroll
        for (int kk = 0; kk < 4; ++kk)
            bfr[g][kk] = *(const f16x8*)(Whhp + (size_t)(((w * 3 + g) * 4 + kk) * 64 + lane) * 8);
    const float bh2 = bhh[256 + 16 * w + c];
    for (int i = tid; i < 2 * 16 * 144 / 2; i += 512) ((unsigned int*)hbuf)[i] = 0u;
    float h[4] = {0.f, 0.f, 0.f, 0.f};

    const int qq = (q < 2) ? q : 1;
    const float* pb = GIt + (size_t)(B * 8 + qq * 4) * 384 + 16 * w + c;
    float g0[12], g1[12], g2[12];
#pragma unroll
    for (int r = 0; r < 4; ++r)
#pragma unroll
        for (int g = 0; g < 3; ++g) {
            g0[r * 3 + g] = pb[r * 384 + g * 128];
            g1[r * 3 + g] = pb[STRIDE + r * 384 + g * 128];
        }
    GRU_SYNC()

    for (int it = 0; it < T_SZ / 6; ++it) {
        GRU_BODY(0, g0, g2, 0)
        GRU_BODY(1, g1, g0, 1)
        GRU_BODY(0, g2, g1, 2)
        GRU_BODY(1, g0, g2, 3)
        GRU_BODY(0, g1, g0, 4)
        GRU_BODY(1, g2, g1, 5)
        pb += 6 * (size_t)STRIDE;
    }

    // ---- block-local classifier: this block owns batches 8B..8B+7 entirely ----
    float* hbf = (float*)hbuf;        // 8 x 128 f32 = 4KB (hbuf no longer needed)
    float* hid = hbf + 1024;          // 8 x 64 f32 = 2KB
    __syncthreads();
    if (q < 2) {
#pragma unroll
        for (int r = 0; r < 4; ++r) hbf[(q * 4 + r) * 128 + 16 * w + c] = h[r];
    }
    __syncthreads();
    {
        const int b = tid >> 6, j = tid & 63;  // 512 threads = 8 batches x 64 cols
        const float* hb = hbf + b * 128;
        float a0 = bc1[j], a1 = 0.f, a2 = 0.f, a3 = 0.f;
#pragma unroll
        for (int k = 0; k < 128; k += 4) {
            a0 = fmaf(hb[k], Wc1[k * 64 + j], a0);
            a1 = fmaf(hb[k + 1], Wc1[(k + 1) * 64 + j], a1);
            a2 = fmaf(hb[k + 2], Wc1[(k + 2) * 64 + j], a2);
            a3 = fmaf(hb[k + 3], Wc1[(k + 3) * 64 + j], a3);
        }
        hid[tid] = fmaxf((a0 + a1) + (a2 + a3), 0.f);
    }
    __syncthreads();
    if (tid < 80) {
        int b = tid / 10, cc2 = tid % 10;
        float a = bc2[cc2];
#pragma unroll 8
        for (int k = 0; k < 64; ++k) a = fmaf(hid[b * 64 + k], Wc2[k * 10 + cc2], a);
        out[(B * 8 + b) * 10 + cc2] = a;
    }
}

extern "C" void kernel_launch(void* const* d_in, const int* in_sizes, int n_in, void* d_out, int out_size, void* d_ws,
                              size_t ws_size, hipStream_t stream) {
    const float* x = (const float*)d_in[0];
    const int* ei = (const int*)d_in[1];
    const int* e_src = ei;
    const int* e_dst = ei + E_TOT;
    const float* W0 = (const float*)d_in[2];
    const float* b0 = (const float*)d_in[3];
    const float* W1 = (const float*)d_in[4];
    const float* b1 = (const float*)d_in[5];
    const float* Wm = (const float*)d_in[6];
    const float* bm = (const float*)d_in[7];
    const float* Wih = (const float*)d_in[8];
    const float* Whh = (const float*)d_in[9];
    const float* bih = (const float*)d_in[10];
    const float* bhh = (const float*)d_in[11];
    const float* Wc1 = (const float*)d_in[12];
    const float* bc1 = (const float*)d_in[13];
    const float* Wc2 = (const float*)d_in[14];
    const float* bc2 = (const float*)d_in[15];
    float* out = (float*)d_out;

    char* base = (char*)d_ws;
    size_t off = 0;
    auto alloc = [&](size_t bytes) {
        size_t o = off;
        off = (off + bytes + 255) & ~(size_t)255;
        return o;
    };
    size_t o_gcur = alloc(256 * 4);
    size_t o_row2 = alloc((size_t)NN_TOT * 8);
    size_t o_er = alloc((size_t)NBINS * CAP * 4);      // padded per-bin src-only records
    size_t o_ertmp = alloc((size_t)NBINS * CAP * 4);   // padded per-bin packed (src|ldst<<18)
    size_t o_xd = alloc((size_t)NN_TOT * 16);
    size_t o_gi = alloc((size_t)(T_SZ + 2) * B_SZ * 384 * 4);  // +2 steps: branchless tail prefetch
    size_t o_wihh = alloc((size_t)384 * 128 * 2);
    size_t o_wihl = alloc((size_t)384 * 128 * 2);
    size_t o_frh = alloc((size_t)B_SZ * T_SZ * 128 * 2);
    size_t o_frl = alloc((size_t)B_SZ * T_SZ * 128 * 2);
    size_t o_w1p = alloc((size_t)128 * 128 * 2);
    size_t o_wmp = alloc((size_t)128 * 128 * 2);
    size_t o_whhp = alloc((size_t)128 * 384 * 2);
    size_t o_w0h = alloc((size_t)384 * 2);
    size_t o_b0h = alloc((size_t)128 * 2);
    size_t o_z0 = alloc((size_t)NN_TOT * 16);
    size_t o_h1 = alloc((size_t)NN_TOT * HID * 2);
    if (off > ws_size) return;

    int* gcur = (int*)(base + o_gcur);
    int2* row2 = (int2*)(base + o_row2);
    int* er = (int*)(base + o_er);
    int* er_tmp = (int*)(base + o_ertmp);
    float4* xd = (float4*)(base + o_xd);
    float* GIt = (float*)(base + o_gi);
    _Float16* Wihh = (_Float16*)(base + o_wihh);
    _Float16* Wihl = (_Float16*)(base + o_wihl);
    _Float16* FRh = (_Float16*)(base + o_frh);
    _Float16* FRl = (_Float16*)(base + o_frl);
    _Float16* W1p = (_Float16*)(base + o_w1p);
    _Float16* Wmp = (_Float16*)(base + o_wmp);
    _Float16* Whhp = (_Float16*)(base + o_whhp);
    _Float16* W0h = (_Float16*)(base + o_w0h);
    _Float16* b0h = (_Float16*)(base + o_b0h);
    float4* z0 = (float4*)(base + o_z0);
    _Float16* h1 = (_Float16*)(base + o_h1);

    hipMemsetAsync(base + o_gcur, 0, 256 * 4, stream);  // zero-seeded bin cursors

    k_scatter<<<NSB + 192, 256, 0, stream>>>(e_src, e_dst, gcur, er_tmp,
                                             Wih, Whh, W1, Wm, W0, b0,
                                             Wihh, Wihl, W1p, Wmp, Whhp, W0h, b0h);
    k_binsort2<<<NBINS, 256, 0, stream>>>(er_tmp, gcur, x, er, row2, xd);
    k_z0<<<NN_TOT / 64, 256, 0, stream>>>(xd, row2, er, z0);
    k_agg_mm<<<NN_TOT / 64, 256, 0, stream>>>(z0, row2, er, W0h, b0h, W1p, b1, h1);
    k_mm_pool<<<B_SZ * T_SZ, 256, 0, stream>>>(h1, Wmp, bm, FRh, FRl);
    k_gi<<<B_SZ * T_SZ / 64, 256, 0, stream>>>(FRh, FRl, Wihh, Wihl, bih, bhh, GIt);
    k_gru<<<4, 512, 0, stream>>>(GIt, Whhp, bhh, Wc1, bc1, Wc2, bc2, out);
}

// Round 10
// 345.779 us; speedup vs baseline: 1.2912x; 1.0386x over previous
//
#include <hip/hip_runtime.h>

#define NN_TOT 208896      // 32*96*68 nodes
#define E_TOT  1671168     // NN_TOT*8 edges
#define B_SZ   32
#define T_SZ   96
#define NPF    68          // nodes per frame
#define HID    128
#define NBINS  204         // 208896 / 1024 nodes per bin
#define CAP    9216        // padded per-bin capacity: mean 8192 + 11 sigma (overflow p ~ 1e-27)
#define NSB    816         // scatter blocks = E_TOT / 2048

typedef _Float16 f16x8 __attribute__((ext_vector_type(8)));
typedef _Float16 f16x2v __attribute__((ext_vector_type(2)));
typedef float f32x4 __attribute__((ext_vector_type(4)));

// ---------------- single-pass scatter into padded bins (+ fused weight prep blocks) ----------------
// Edge records packed to 4B: src (18b) | local-dst (10b) << 18. Blocks [0,816): LDS-hist scatter
// into er_tmp[bin*CAP + cursor] (gcur zero-seeded). Blocks [816,1008): weight prep.
__global__ __launch_bounds__(256) void k_scatter(const int* __restrict__ src, const int* __restrict__ dst,
                                                 int* __restrict__ gcur, int* __restrict__ er_tmp,
                                                 const float* __restrict__ Wih, const float* __restrict__ Whh,
                                                 const float* __restrict__ W1, const float* __restrict__ Wm,
                                                 const float* __restrict__ W0, const float* __restrict__ b0,
                                                 _Float16* __restrict__ Wihh, _Float16* __restrict__ Wihl,
                                                 _Float16* __restrict__ W1p, _Float16* __restrict__ Wmp,
                                                 _Float16* __restrict__ Whhp, _Float16* __restrict__ W0h,
                                                 _Float16* __restrict__ b0h) {
    const int bid = blockIdx.x;
    const int tid = threadIdx.x;
    if (bid >= NSB) {
        // ---- weight prep (uniform per-block branch) ----
        int i = (bid - NSB) * 256 + tid;  // 0..49151
        {
            // Wih split-f16 frag pack: B[k][o] = Wih[o][k]; f = j*4+kk, j=0..23 (N=384)
            int e = i & 7;
            int lane = (i >> 3) & 63;
            int f = i >> 9;  // 0..95
            int j = f >> 2, kk = f & 3;
            int q = lane >> 4, p = lane & 15;
            float wv = Wih[(size_t)(j * 16 + p) * 128 + kk * 32 + q * 8 + e];
            _Float16 hi = (_Float16)wv;
            Wihh[i] = hi;
            Wihl[i] = (_Float16)(wv - (float)hi);
        }
        {
            // Whh frag pack: i = (f*64 + lane)*8 + e, f = (wv*3+g)*4+kk
            int e = i & 7;
            int lane = (i >> 3) & 63;
            int f = i >> 9;  // 0..95
            int kk = f & 3, g = (f >> 2) % 3, wv = f / 12;
            int q = lane >> 4, c = lane & 15;
            Whhp[i] = (_Float16)Whh[(size_t)(g * 128 + 16 * wv + c) * 128 + kk * 32 + q * 8 + e];
        }
        if (i < 16384) {
            int f = i >> 9;          // frag id 0..31
            int j = f >> 2, kk = f & 3;
            int lane = (i >> 3) & 63;
            int e = i & 7;
            int q = lane >> 4, p = lane & 15;
            int k = kk * 32 + q * 8 + e, n = j * 16 + p;
            W1p[i] = (_Float16)W1[k * 128 + n];
            Wmp[i] = (_Float16)Wm[k * 128 + n];
        }
        if (i < 384) W0h[i] = (_Float16)W0[i];
        if (i < 128) b0h[i] = (_Float16)b0[i];
        return;
    }
    __shared__ int hist[NBINS];
    __shared__ int lbase[NBINS];
    for (int i = tid; i < NBINS; i += 256) hist[i] = 0;
    __syncthreads();
    const int be = bid * 2048 + tid * 8;
    int s[8], d[8], rk[8];
    *(int4*)&s[0] = *(const int4*)&src[be];
    *(int4*)&s[4] = *(const int4*)&src[be + 4];
    *(int4*)&d[0] = *(const int4*)&dst[be];
    *(int4*)&d[4] = *(const int4*)&dst[be + 4];
#pragma unroll
    for (int j = 0; j < 8; ++j) rk[j] = atomicAdd(&hist[d[j] >> 10], 1);
    __syncthreads();
    for (int i = tid; i < NBINS; i += 256) lbase[i] = atomicAdd(&gcur[i], hist[i]);
    __syncthreads();
#pragma unroll
    for (int j = 0; j < 8; ++j) {
        int b = d[j] >> 10;
        er_tmp[(size_t)b * CAP + lbase[b] + rk[j]] = s[j] | ((d[j] & 1023) << 18);
    }
}

// ---------------- CSR pass C: records register-cached (single global read), LDS count+scan ----
// row2[n] = (beg,end) in padded er coords; xd[i] = (x*is, is) — factorized GCN norm.
__global__ __launch_bounds__(256) void k_binsort2(const int* __restrict__ er_tmp, const int* __restrict__ gcur,
                                                  const float* __restrict__ x, int* __restrict__ er,
                                                  int2* __restrict__ row2, float4* __restrict__ xd) {
    __shared__ int lcnt[1024];
    __shared__ int lofs[1024];
    __shared__ int ts[256];
    const int tid = threadIdx.x;
    const int nb = blockIdx.x << 10;
    const int base0 = blockIdx.x * CAP;
    for (int i = tid; i < 1024; i += 256) lcnt[i] = 0;
    __syncthreads();
    const int nrec = gcur[blockIdx.x];
    // load all bin records once into registers (static unroll -> VGPRs, rule #20)
    int rec[36];  // 36*256 == CAP
#pragma unroll
    for (int j = 0; j < 36; ++j) {
        int idx = tid + j * 256;
        rec[j] = (idx < nrec) ? er_tmp[base0 + idx] : -1;
    }
#pragma unroll
    for (int j = 0; j < 36; ++j)
        if (rec[j] >= 0) atomicAdd(&lcnt[rec[j] >> 18], 1);
    __syncthreads();
    const int base = tid * 4;
    const int c0 = lcnt[base], c1 = lcnt[base + 1], c2 = lcnt[base + 2], c3 = lcnt[base + 3];
    int ssum = c0 + c1 + c2 + c3;
    ts[tid] = ssum;
    __syncthreads();
    int inc = ssum;
    for (int off = 1; off < 256; off <<= 1) {
        int add = (tid >= off) ? ts[tid - off] : 0;
        __syncthreads();
        inc += add;
        ts[tid] = inc;
        __syncthreads();
    }
    const int b0 = base0 + (inc - ssum);  // padded-coord exclusive offset of node base
    lofs[base] = b0;
    lofs[base + 1] = b0 + c0;
    lofs[base + 2] = b0 + c0 + c1;
    lofs[base + 3] = b0 + c0 + c1 + c2;
    row2[nb + base] = make_int2(b0, b0 + c0);
    row2[nb + base + 1] = make_int2(b0 + c0, b0 + c0 + c1);
    row2[nb + base + 2] = make_int2(b0 + c0 + c1, b0 + c0 + c1 + c2);
    row2[nb + base + 3] = make_int2(b0 + c0 + c1 + c2, b0 + ssum);
    // xd pack: 12 contiguous floats = 3 float4 per thread (48B aligned)
    {
        const float4* xv = (const float4*)(x + 3 * (size_t)(nb + base));
        float4 a = xv[0], b = xv[1], c = xv[2];
        float i0 = 1.0f / sqrtf(1.f + (float)c0);
        float i1 = 1.0f / sqrtf(1.f + (float)c1);
        float i2 = 1.0f / sqrtf(1.f + (float)c2);
        float i3 = 1.0f / sqrtf(1.f + (float)c3);
        xd[nb + base + 0] = make_float4(a.x * i0, a.y * i0, a.z * i0, i0);
        xd[nb + base + 1] = make_float4(a.w * i1, b.x * i1, b.y * i1, i1);
        xd[nb + base + 2] = make_float4(b.z * i2, b.w * i2, c.x * i2, i2);
        xd[nb + base + 3] = make_float4(c.y * i3, c.z * i3, c.w * i3, i3);
    }
    __syncthreads();
#pragma unroll
    for (int j = 0; j < 36; ++j)
        if (rec[j] >= 0) {
            int p = atomicAdd(&lofs[rec[j] >> 18], 1);
            er[p] = rec[j] & 0x3FFFF;  // src only: norm factorized via xd/z0.w
        }
}

// ---------------- z0: 3-dim GCN0 aggregate, factorized norm ----------------
__global__ __launch_bounds__(256) void k_z0(const float4* __restrict__ xd, const int2* __restrict__ row2,
                                            const int* __restrict__ er, float4* __restrict__ z0out) {
    const int tid = threadIdx.x;
    const int blk = blockIdx.x;
    const int li = tid >> 2;
    const int slot = tid & 3;
    const int n = blk * 64 + li;
    const int2 be2 = row2[n];
    float p0 = 0.f, p1 = 0.f, p2 = 0.f;
    for (int ei = be2.x + slot; ei < be2.y; ei += 4) {
        float4 f = xd[er[ei]];
        p0 += f.x;
        p1 += f.y;
        p2 += f.z;
    }
    p0 += __shfl_xor(p0, 1); p1 += __shfl_xor(p1, 1); p2 += __shfl_xor(p2, 1);
    p0 += __shfl_xor(p0, 2); p1 += __shfl_xor(p1, 2); p2 += __shfl_xor(p2, 2);
    if (slot == 0) {
        const float4 own = xd[n];
        const float w = own.w;
        float4 z;
        z.x = w * (p0 + own.x);
        z.y = w * (p1 + own.y);
        z.z = w * (p2 + own.z);
        z.w = w;
        z0out[n] = z;
    }
}

// ---------------- fused: aggregation + GEMM1 + GEMM2 + frame-pool atomics (h1 eliminated) --------
// Phase 1: edge-loop h0 recompute -> As (f16, 136-stride). Phase 2: C1 = relu(As@W1p+b1) -> Bs.
// Phase 3: C2 = relu(Bs@Wmp+bm); per-frame segmented column sums (block spans <=2 frames) ->
// atomicAdd into fr32[frame][128]. k_mm_pool and the 107MB h1 round trip are gone.
__global__ __launch_bounds__(256, 4) void k_agg_mm(const float4* __restrict__ z0, const int2* __restrict__ row2,
                                                   const int* __restrict__ er, const _Float16* __restrict__ W0h,
                                                   const _Float16* __restrict__ b0h, const _Float16* __restrict__ W1p,
                                                   const float* __restrict__ b1, const _Float16* __restrict__ Wmp,
                                                   const float* __restrict__ bm, float* __restrict__ fr32) {
    __shared__ __align__(16) _Float16 As[64 * 136];
    __shared__ __align__(16) _Float16 Bs[64 * 136];
    __shared__ float colpart[4 * 2 * 128];  // [wave][frame 0/1][col]
    const int tid = threadIdx.x;
    const int w = tid >> 6, lane = tid & 63;
    const int blk = blockIdx.x;

    // phase 1: per-lane edge loop, packed f16, all 32 cols in one pass
    {
        const int node = blk * 64 + lane;
        const int2 be2 = row2[node];
        const int beg = be2.x, end = be2.y;
        const f16x2v* __restrict__ W0p = (const f16x2v*)W0h;
        const f16x2v* __restrict__ b0p = (const f16x2v*)b0h;
        const int pb = w * 16;
        const f16x2v zero2 = {(_Float16)0.f, (_Float16)0.f};
        f16x2v w0p[16], w1p[16], w2p[16], bbp[16];
#pragma unroll
        for (int j = 0; j < 16; ++j) {
            w0p[j] = W0p[pb + j];
            w1p[j] = W0p[64 + pb + j];
            w2p[j] = W0p[128 + pb + j];
            bbp[j] = b0p[pb + j];
        }
        const float4 zs = z0[node];
        const _Float16 isd = (_Float16)zs.w;
        const f16x2v dnn = {isd, isd};
        f16x2v accp[16];
        {
            _Float16 sx = (_Float16)zs.x, sy = (_Float16)zs.y, sz = (_Float16)zs.z;
            f16x2v zxx = {sx, sx}, zyy = {sy, sy}, zzz = {sz, sz};
#pragma unroll
            for (int j = 0; j < 16; ++j) {
                f16x2v t = zxx * w0p[j] + (zyy * w1p[j] + (zzz * w2p[j] + bbp[j]));
                t = __builtin_elementwise_max(t, zero2);
                accp[j] = t * dnn;
            }
        }
        int ei = beg;
        for (; ei + 2 <= end; ei += 2) {
            int sa = er[ei], sb = er[ei + 1];
            float4 za = z0[sa];
            float4 zb = z0[sb];
            _Float16 ax = (_Float16)za.x, ay = (_Float16)za.y, az = (_Float16)za.z;
            _Float16 aen = (_Float16)za.w;
            _Float16 bx = (_Float16)zb.x, by = (_Float16)zb.y, bz = (_Float16)zb.z;
            _Float16 ben = (_Float16)zb.w;
            f16x2v axx = {ax, ax}, ayy = {ay, ay}, azz = {az, az}, aee = {aen, aen};
            f16x2v bxx = {bx, bx}, byy = {by, by}, bzz = {bz, bz}, bee = {ben, ben};
#pragma unroll
            for (int j = 0; j < 16; ++j) {
                f16x2v t = axx * w0p[j] + (ayy * w1p[j] + (azz * w2p[j] + bbp[j]));
                t = __builtin_elementwise_max(t, zero2);
                accp[j] = t * aee + accp[j];
            }
#pragma unroll
            for (int j = 0; j < 16; ++j) {
                f16x2v t = bxx * w0p[j] + (byy * w1p[j] + (bzz * w2p[j] + bbp[j]));
                t = __builtin_elementwise_max(t, zero2);
                accp[j] = t * bee + accp[j];
            }
        }
        if (ei < end) {
            float4 za = z0[er[ei]];
            _Float16 ax = (_Float16)za.x, ay = (_Float16)za.y, az = (_Float16)za.z;
            _Float16 aen = (_Float16)za.w;
            f16x2v axx = {ax, ax}, ayy = {ay, ay}, azz = {az, az}, aee = {aen, aen};
#pragma unroll
            for (int j = 0; j < 16; ++j) {
                f16x2v t = axx * w0p[j] + (ayy * w1p[j] + (azz * w2p[j] + bbp[j]));
                t = __builtin_elementwise_max(t, zero2);
                accp[j] = t * aee + accp[j];
            }
        }
        _Float16* dst = &As[lane * 136 + w * 32];
#pragma unroll
        for (int j = 0; j < 16; ++j) *(f16x2v*)(dst + 2 * j) = accp[j] * dnn;
    }
    __syncthreads();

    // phase 2: GEMM1 (As @ W1p + b1, relu) -> Bs (wave-local rows, 136-stride)
    const int q = lane >> 4, c = lane & 15;
    {
        f16x8 afr[4];
#pragma unroll
        for (int kk = 0; kk < 4; ++kk) afr[kk] = *(const f16x8*)(&As[(w * 16 + c) * 136 + kk * 32 + q * 8]);
        const f16x8* __restrict__ Bv = (const f16x8*)W1p;
#pragma unroll
        for (int j = 0; j < 8; ++j) {
            f32x4 cc = {0.f, 0.f, 0.f, 0.f};
#pragma unroll
            for (int kk = 0; kk < 4; ++kk)
                cc = __builtin_amdgcn_mfma_f32_16x16x32_f16(afr[kk], Bv[(j * 4 + kk) * 64 + lane], cc, 0, 0, 0);
            const float bi = b1[j * 16 + c];
#pragma unroll
            for (int r = 0; r < 4; ++r)
                Bs[(w * 16 + q * 4 + r) * 136 + j * 16 + c] = (_Float16)fmaxf(cc[r] + bi, 0.f);
        }
    }
    // Bs rows w*16..w*16+15 are wave-local (written and read by wave w) -> no barrier needed.

    // phase 3: GEMM2 (Bs @ Wmp + bm, relu) + segmented per-frame column sums
    {
        f16x8 afr2[4];
#pragma unroll
        for (int kk = 0; kk < 4; ++kk) afr2[kk] = *(const f16x8*)(&Bs[(w * 16 + c) * 136 + kk * 32 + q * 8]);
        const f16x8* __restrict__ Bv2 = (const f16x8*)Wmp;
        const int f0 = (blk * 64) / NPF;
        const int cut = (f0 + 1) * NPF;          // first node of frame f0+1
        const int rowg0 = blk * 64 + w * 16 + q * 4;
#pragma unroll
        for (int j = 0; j < 8; ++j) {
            f32x4 cc = {0.f, 0.f, 0.f, 0.f};
#pragma unroll
            for (int kk = 0; kk < 4; ++kk)
                cc = __builtin_amdgcn_mfma_f32_16x16x32_f16(afr2[kk], Bv2[(j * 4 + kk) * 64 + lane], cc, 0, 0, 0);
            const float bi = bm[j * 16 + c];
            float sA = 0.f, sB = 0.f;
#pragma unroll
            for (int r = 0; r < 4; ++r) {
                float v = fmaxf(cc[r] + bi, 0.f);
                if (rowg0 + r < cut) sA += v; else sB += v;
            }
            sA += __shfl_xor(sA, 16);
            sA += __shfl_xor(sA, 32);
            sB += __shfl_xor(sB, 16);
            sB += __shfl_xor(sB, 32);
            if (lane < 16) {
                colpart[(w * 2 + 0) * 128 + j * 16 + c] = sA;
                colpart[(w * 2 + 1) * 128 + j * 16 + c] = sB;
            }
        }
    }
    __syncthreads();
    {
        const int f = tid >> 7, col = tid & 127;  // 256 threads = 2 frames x 128 cols
        float s = colpart[(0 * 2 + f) * 128 + col] + colpart[(1 * 2 + f) * 128 + col] +
                  colpart[(2 * 2 + f) * 128 + col] + colpart[(3 * 2 + f) * 128 + col];
        const int f0 = (blk * 64) / NPF;
        if (f == 0) {
            atomicAdd(&fr32[(size_t)f0 * 128 + col], s);
        } else {
            const int f1 = (blk * 64 + 63) / NPF;
            if (f1 != f0) atomicAdd(&fr32[(size_t)f1 * 128 + col], s);
        }
    }
}

// ---------------- gi GEMM: fr32 (mean-scaled, split to hi/lo f16 in-LDS) @ Wih^T -> GIt ----
__global__ __launch_bounds__(256) void k_gi(const float* __restrict__ fr32,
                                            const _Float16* __restrict__ Wihh, const _Float16* __restrict__ Wihl,
                                            const float* __restrict__ bih, const float* __restrict__ bhh,
                                            float* __restrict__ GIt) {
    __shared__ __align__(16) _Float16 Ah[64 * 136];
    __shared__ __align__(16) _Float16 Al[64 * 136];
    const int tid = threadIdx.x;
    const int w = tid >> 6, lane = tid & 63;
    const int q = lane >> 4, p = lane & 15;
    const int nb = blockIdx.x * 64;

    for (int idx = tid; idx < 64 * 128; idx += 256) {
        int row = idx >> 7, col = idx & 127;
        float v = fr32[(size_t)(nb + row) * 128 + col] * (1.0f / NPF);
        _Float16 hi = (_Float16)v;
        Ah[row * 136 + col] = hi;
        Al[row * 136 + col] = (_Float16)(v - (float)hi);
    }
    __syncthreads();

    f16x8 ah[4], al[4];
#pragma unroll
    for (int kk = 0; kk < 4; ++kk) {
        ah[kk] = *(const f16x8*)(&Ah[(w * 16 + p) * 136 + kk * 32 + q * 8]);
        al[kk] = *(const f16x8*)(&Al[(w * 16 + p) * 136 + kk * 32 + q * 8]);
    }
    const f16x8* __restrict__ Bh = (const f16x8*)Wihh;
    const f16x8* __restrict__ Bl = (const f16x8*)Wihl;
    int dr[4];
#pragma unroll
    for (int r = 0; r < 4; ++r) {
        int m = nb + w * 16 + q * 4 + r;
        int bb = m / 96, tt = m - bb * 96;
        dr[r] = (tt * B_SZ + bb) * 384;
    }
#pragma unroll
    for (int j = 0; j < 24; ++j) {
        f32x4 cc = {0.f, 0.f, 0.f, 0.f};
#pragma unroll
        for (int kk = 0; kk < 4; ++kk)
            cc = __builtin_amdgcn_mfma_f32_16x16x32_f16(ah[kk], Bh[(j * 4 + kk) * 64 + lane], cc, 0, 0, 0);
#pragma unroll
        for (int kk = 0; kk < 4; ++kk)
            cc = __builtin_amdgcn_mfma_f32_16x16x32_f16(ah[kk], Bl[(j * 4 + kk) * 64 + lane], cc, 0, 0, 0);
#pragma unroll
        for (int kk = 0; kk < 4; ++kk)
            cc = __builtin_amdgcn_mfma_f32_16x16x32_f16(al[kk], Bh[(j * 4 + kk) * 64 + lane], cc, 0, 0, 0);
        const int o = j * 16 + p;
        const float bias = bih[o] + ((o < 256) ? bhh[o] : 0.f);
        const float scale = (o < 256) ? -1.44269504f : 1.f;
#pragma unroll
        for (int r = 0; r < 4; ++r) GIt[dr[r] + o] = (cc[r] + bias) * scale;
    }
}

// ---------------- GRU recurrence (+ block-local classifier: hT never leaves the block) ------
#define GRU_SYNC()                                              \
    asm volatile("s_waitcnt lgkmcnt(0)" ::: "memory");          \
    __builtin_amdgcn_s_barrier();                               \
    __builtin_amdgcn_sched_barrier(0);

#define GRU_BODY(PAR, GU, GL, JOFF)                                                                  \
    {                                                                                                \
        const _Float16* rb = hbuf[PAR];                                                              \
        _Float16* wb = hbuf[PAR ^ 1];                                                                \
        f16x8 afr[4];                                                                                \
        _Pragma("unroll") for (int kk = 0; kk < 4; ++kk)                                             \
            afr[kk] = *(const f16x8*)(&rb[c * 144 + kk * 32 + q * 8]);                               \
        const float* lp = pb + (size_t)(JOFF + 2) * STRIDE;                                          \
        _Pragma("unroll") for (int r = 0; r < 4; ++r)                                                \
            _Pragma("unroll") for (int g = 0; g < 3; ++g)                                            \
                GL[r * 3 + g] = lp[r * 384 + g * 128];                                               \
        f32x4 cc[3];                                                                                 \
        _Pragma("unroll") for (int g = 0; g < 3; ++g) {                                              \
            f32x4 a = {0.f, 0.f, 0.f, 0.f};                                                          \
            _Pragma("unroll") for (int kk = 0; kk < 4; ++kk)                                         \
                a = __builtin_amdgcn_mfma_f32_16x16x32_f16(afr[kk], bfr[g][kk], a, 0, 0, 0);         \
            cc[g] = a;                                                                               \
        }                                                                                            \
        _Pragma("unroll") for (int r = 0; r < 4; ++r) {                                              \
            float hn = cc[2][r] + bh2;                                                               \
            float rg = __builtin_amdgcn_rcpf(1.f + exp2f(fmaf(mL2E, cc[0][r], GU[r * 3 + 0])));      \
            float zg = __builtin_amdgcn_rcpf(1.f + exp2f(fmaf(mL2E, cc[1][r], GU[r * 3 + 1])));      \
            float arg = fmaf(rg, hn, GU[r * 3 + 2]);                                                 \
            float u = __builtin_amdgcn_rcpf(exp2f(2.f * L2E * arg) + 1.f);                           \
            float nn = fmaf(-2.f, u, 1.f);                                                           \
            h[r] = fmaf(zg, h[r] - nn, nn);                                                          \
            if (q < 2) wb[(q * 4 + r) * 144 + 16 * w + c] = (_Float16)h[r];                          \
        }                                                                                            \
        GRU_SYNC()                                                                                   \
    }

__global__ __launch_bounds__(512) __attribute__((amdgpu_waves_per_eu(1, 2)))
void k_gru(const float* __restrict__ GIt, const _Float16* __restrict__ Whhp,
           const float* __restrict__ bhh,
           const float* __restrict__ Wc1, const float* __restrict__ bc1,
           const float* __restrict__ Wc2, const float* __restrict__ bc2,
           float* __restrict__ out) {
    __shared__ __align__(16) _Float16 hbuf[2][16 * 144];
    const int tid = threadIdx.x;
    const int w = tid >> 6, lane = tid & 63;
    const int q = lane >> 4, c = lane & 15;
    const int B = blockIdx.x;  // batches 8B..8B+7
    const float L2E = 1.44269504f;
    const float mL2E = -1.44269504f;
    const int STRIDE = B_SZ * 384;

    f16x8 bfr[3][4];
#pragma unroll
    for (int g = 0; g < 3; ++g)
#pragma unroll
        for (int kk = 0; kk < 4; ++kk)
            bfr[g][kk] = *(const f16x8*)(Whhp + (size_t)(((w * 3 + g) * 4 + kk) * 64 + lane) * 8);
    const float bh2 = bhh[256 + 16 * w + c];
    for (int i = tid; i < 2 * 16 * 144 / 2; i += 512) ((unsigned int*)hbuf)[i] = 0u;
    float h[4] = {0.f, 0.f, 0.f, 0.f};

    const int qq = (q < 2) ? q : 1;
    const float* pb = GIt + (size_t)(B * 8 + qq * 4) * 384 + 16 * w + c;
    float g0[12], g1[12], g2[12];
#pragma unroll
    for (int r = 0; r < 4; ++r)
#pragma unroll
        for (int g = 0; g < 3; ++g) {
            g0[r * 3 + g] = pb[r * 384 + g * 128];
            g1[r * 3 + g] = pb[STRIDE + r * 384 + g * 128];
        }
    GRU_SYNC()

    for (int it = 0; it < T_SZ / 6; ++it) {
        GRU_BODY(0, g0, g2, 0)
        GRU_BODY(1, g1, g0, 1)
        GRU_BODY(0, g2, g1, 2)
        GRU_BODY(1, g0, g2, 3)
        GRU_BODY(0, g1, g0, 4)
        GRU_BODY(1, g2, g1, 5)
        pb += 6 * (size_t)STRIDE;
    }

    // ---- block-local classifier: this block owns batches 8B..8B+7 entirely ----
    float* hbf = (float*)hbuf;        // 8 x 128 f32 = 4KB (hbuf no longer needed)
    float* hid = hbf + 1024;          // 8 x 64 f32 = 2KB
    __syncthreads();
    if (q < 2) {
#pragma unroll
        for (int r = 0; r < 4; ++r) hbf[(q * 4 + r) * 128 + 16 * w + c] = h[r];
    }
    __syncthreads();
    {
        const int b = tid >> 6, j = tid & 63;  // 512 threads = 8 batches x 64 cols
        const float* hb = hbf + b * 128;
        float a0 = bc1[j], a1 = 0.f, a2 = 0.f, a3 = 0.f;
#pragma unroll
        for (int k = 0; k < 128; k += 4) {
            a0 = fmaf(hb[k], Wc1[k * 64 + j], a0);
            a1 = fmaf(hb[k + 1], Wc1[(k + 1) * 64 + j], a1);
            a2 = fmaf(hb[k + 2], Wc1[(k + 2) * 64 + j], a2);
            a3 = fmaf(hb[k + 3], Wc1[(k + 3) * 64 + j], a3);
        }
        hid[tid] = fmaxf((a0 + a1) + (a2 + a3), 0.f);
    }
    __syncthreads();
    if (tid < 80) {
        int b = tid / 10, cc2 = tid % 10;
        float a = bc2[cc2];
#pragma unroll 8
        for (int k = 0; k < 64; ++k) a = fmaf(hid[b * 64 + k], Wc2[k * 10 + cc2], a);
        out[(B * 8 + b) * 10 + cc2] = a;
    }
}

extern "C" void kernel_launch(void* const* d_in, const int* in_sizes, int n_in, void* d_out, int out_size, void* d_ws,
                              size_t ws_size, hipStream_t stream) {
    const float* x = (const float*)d_in[0];
    const int* ei = (const int*)d_in[1];
    const int* e_src = ei;
    const int* e_dst = ei + E_TOT;
    const float* W0 = (const float*)d_in[2];
    const float* b0 = (const float*)d_in[3];
    const float* W1 = (const float*)d_in[4];
    const float* b1 = (const float*)d_in[5];
    const float* Wm = (const float*)d_in[6];
    const float* bm = (const float*)d_in[7];
    const float* Wih = (const float*)d_in[8];
    const float* Whh = (const float*)d_in[9];
    const float* bih = (const float*)d_in[10];
    const float* bhh = (const float*)d_in[11];
    const float* Wc1 = (const float*)d_in[12];
    const float* bc1 = (const float*)d_in[13];
    const float* Wc2 = (const float*)d_in[14];
    const float* bc2 = (const float*)d_in[15];
    float* out = (float*)d_out;

    char* base = (char*)d_ws;
    size_t off = 0;
    auto alloc = [&](size_t bytes) {
        size_t o = off;
        off = (off + bytes + 255) & ~(size_t)255;
        return o;
    };
    size_t o_gcur = alloc(256 * 4);
    size_t o_row2 = alloc((size_t)NN_TOT * 8);
    size_t o_er = alloc((size_t)NBINS * CAP * 4);      // padded per-bin src-only records
    size_t o_ertmp = alloc((size_t)NBINS * CAP * 4);   // padded per-bin packed (src|ldst<<18)
    size_t o_xd = alloc((size_t)NN_TOT * 16);
    size_t o_fr32 = alloc((size_t)B_SZ * T_SZ * 128 * 4);      // frame pool accumulator (f32)
    size_t o_gi = alloc((size_t)(T_SZ + 2) * B_SZ * 384 * 4);  // +2 steps: branchless tail prefetch
    size_t o_wihh = alloc((size_t)384 * 128 * 2);
    size_t o_wihl = alloc((size_t)384 * 128 * 2);
    size_t o_w1p = alloc((size_t)128 * 128 * 2);
    size_t o_wmp = alloc((size_t)128 * 128 * 2);
    size_t o_whhp = alloc((size_t)128 * 384 * 2);
    size_t o_w0h = alloc((size_t)384 * 2);
    size_t o_b0h = alloc((size_t)128 * 2);
    size_t o_z0 = alloc((size_t)NN_TOT * 16);
    if (off > ws_size) return;

    int* gcur = (int*)(base + o_gcur);
    int2* row2 = (int2*)(base + o_row2);
    int* er = (int*)(base + o_er);
    int* er_tmp = (int*)(base + o_ertmp);
    float4* xd = (float4*)(base + o_xd);
    float* fr32 = (float*)(base + o_fr32);
    float* GIt = (float*)(base + o_gi);
    _Float16* Wihh = (_Float16*)(base + o_wihh);
    _Float16* Wihl = (_Float16*)(base + o_wihl);
    _Float16* W1p = (_Float16*)(base + o_w1p);
    _Float16* Wmp = (_Float16*)(base + o_wmp);
    _Float16* Whhp = (_Float16*)(base + o_whhp);
    _Float16* W0h = (_Float16*)(base + o_w0h);
    _Float16* b0h = (_Float16*)(base + o_b0h);
    float4* z0 = (float4*)(base + o_z0);

    hipMemsetAsync(base + o_gcur, 0, 256 * 4, stream);                         // bin cursors
    hipMemsetAsync(base + o_fr32, 0, (size_t)B_SZ * T_SZ * 128 * 4, stream);   // pool accumulator

    k_scatter<<<NSB + 192, 256, 0, stream>>>(e_src, e_dst, gcur, er_tmp,
                                             Wih, Whh, W1, Wm, W0, b0,
                                             Wihh, Wihl, W1p, Wmp, Whhp, W0h, b0h);
    k_binsort2<<<NBINS, 256, 0, stream>>>(er_tmp, gcur, x, er, row2, xd);
    k_z0<<<NN_TOT / 64, 256, 0, stream>>>(xd, row2, er, z0);
    k_agg_mm<<<NN_TOT / 64, 256, 0, stream>>>(z0, row2, er, W0h, b0h, W1p, b1, Wmp, bm, fr32);
    k_gi<<<B_SZ * T_SZ / 64, 256, 0, stream>>>(fr32, Wihh, Wihl, bih, bhh, GIt);
    k_gru<<<4, 512, 0, stream>>>(GIt, Whhp, bhh, Wc1, bc1, Wc2, bc2, out);
}